// Round 6
// baseline (316.843 us; speedup 1.0000x reference)
//
#include <hip/hip_runtime.h>

#define NN 50000
#define EE 800000
#define FF 128
#define HH 4
#define BB 8
#define NEG 0.2f
#define NBLK ((NN + 255) / 256)   // 196

typedef __attribute__((ext_vector_type(8))) short s8v;
typedef __attribute__((ext_vector_type(4))) float f4v;

__device__ __forceinline__ unsigned short f2b(float f) {
    union { float f; unsigned u; } v; v.f = f;
    unsigned r = v.u + 0x7fffu + ((v.u >> 16) & 1u);
    return (unsigned short)(r >> 16);
}
__device__ __forceinline__ float b2f(unsigned short h) {
    union { unsigned u; float f; } v; v.u = ((unsigned)h) << 16;
    return v.f;
}
__device__ __forceinline__ float uasf(unsigned u) {
    union { unsigned u; float f; } v; v.u = u; return v.f;
}
__device__ __forceinline__ float lrelu(float t) { return t > 0.f ? t : NEG * t; }

// ---------------- init: cur=1 (self loop), pooled=0 ----------------
__global__ void k_init(int* cur, float* pooled) {
    int i = blockIdx.x * 256 + threadIdx.x;
    if (i < NN) cur[i] = 1;
    if (i < BB * FF) pooled[i] = 0.f;
}

// ---------------- count in-degree ----------------
__global__ void k_count(const int* __restrict__ ei, int* cur) {
    int i = blockIdx.x * 256 + threadIdx.x;
    if (i < EE) atomicAdd(&cur[ei[EE + i]], 1);
}

// ---------------- 3-phase parallel scan ----------------
__global__ __launch_bounds__(256) void k_scanA(int* cur, int* row_ptr, int* bsum) {
    __shared__ int wsum[4];
    int b = blockIdx.x, t = threadIdx.x;
    int i = b * 256 + t;
    int v = (i < NN) ? cur[i] : 0;
    if (i < NN) cur[i] = 0;
    int lane = t & 63, w = t >> 6;
    int sc = v;
#pragma unroll
    for (int off = 1; off < 64; off <<= 1) {
        int n = __shfl_up(sc, off);
        if (lane >= off) sc += n;
    }
    if (lane == 63) wsum[w] = sc;
    __syncthreads();
    int woff = 0;
    for (int k = 0; k < w; k++) woff += wsum[k];
    int incl = sc + woff;
    if (i < NN) row_ptr[i + 1] = incl;
    if (t == 255) bsum[b] = incl;
    if (i == 0) row_ptr[0] = 0;
}

__global__ __launch_bounds__(256) void k_scanB(const int* __restrict__ bsum, int* boff) {
    __shared__ int wsum[4];
    int t = threadIdx.x;
    int v = (t < NBLK) ? bsum[t] : 0;
    int lane = t & 63, w = t >> 6;
    int sc = v;
#pragma unroll
    for (int off = 1; off < 64; off <<= 1) {
        int n = __shfl_up(sc, off);
        if (lane >= off) sc += n;
    }
    if (lane == 63) wsum[w] = sc;
    __syncthreads();
    int woff = 0;
    for (int k = 0; k < w; k++) woff += wsum[k];
    if (t < NBLK) boff[t] = sc + woff - v;
}

__global__ __launch_bounds__(256) void k_scanC(int* row_ptr, const int* __restrict__ boff) {
    int i = blockIdx.x * 256 + threadIdx.x;
    if (i < NN) row_ptr[i + 1] += boff[blockIdx.x];
}

// ---------------- scatter edges (and self loops) into CSR ----------------
__global__ void k_scatter(const int* __restrict__ ei, const int* __restrict__ row_ptr,
                          int* cur, int* col) {
    int i = blockIdx.x * 256 + threadIdx.x;
    if (i < EE) {
        int s = ei[i], d = ei[EE + i];
        int p = atomicAdd(&cur[d], 1);
        col[row_ptr[d] + p] = s;
    } else if (i < EE + NN) {
        int n = i - EE;
        int p = atomicAdd(&cur[n], 1);
        col[row_ptr[n] + p] = n;
    }
}

// ---------------- weight transpose+convert to bf16 ----------------
__global__ void k_convw(const float* __restrict__ locW, const float* __restrict__ regW,
                        const float* __restrict__ W1, const float* __restrict__ W2,
                        unsigned short* __restrict__ Wt, unsigned short* __restrict__ W1t,
                        unsigned short* __restrict__ W2t) {
    int i = blockIdx.x * 256 + threadIdx.x;
    if (i < 32768) {
        int n = i >> 7, k = i & 127;
        float v = n < 128 ? locW[k * 128 + n] : regW[k * 128 + n - 128];
        Wt[i] = f2b(v);
    } else if (i < 32768 + 98304) {
        int j = i - 32768; int n = j / 384, k = j - n * 384;
        W1t[j] = f2b(W1[k * 256 + n]);
    } else if (i < 163840) {
        int j = i - 131072; int n = j >> 8, k = j & 255;
        W2t[j] = f2b(W2[k * 128 + n]);
    }
}

// ---------------- GEMM1 (MFMA): h = bf16(x) @ W -> interleaved hc; alpha epilogue ----------------
__global__ __launch_bounds__(256) void k_gemm1(
    const float* __restrict__ x,
    const unsigned short* __restrict__ Wt,
    const float* __restrict__ loc_as, const float* __restrict__ loc_ad,
    const float* __restrict__ reg_as, const float* __restrict__ reg_ad,
    unsigned* __restrict__ hc,
    float* __restrict__ als_l, float* __restrict__ ald_l,
    float* __restrict__ als_r, float* __restrict__ ald_r) {
    __shared__ unsigned short As[4 * 64 * 8];
    __shared__ unsigned short Bs[4 * 256 * 8];
    __shared__ unsigned short Hs[32 * 64 * 8];
    int t = threadIdx.x;
    int w = t >> 6, l = t & 63;
    int lq = l >> 4, lr = l & 15;
    int r0 = blockIdx.x * 64;

    int srow = t >> 2, sg = t & 3;
    int snode = r0 + srow; if (snode >= NN) snode = NN - 1;
    const float* xrow = x + (size_t)snode * 128 + sg * 8;

    f4v acc[4][4];
#pragma unroll
    for (int a0 = 0; a0 < 4; a0++)
#pragma unroll
        for (int b0 = 0; b0 < 4; b0++) acc[a0][b0] = (f4v){0.f, 0.f, 0.f, 0.f};

    for (int ks = 0; ks < 4; ++ks) {
        {
            float4 f0 = *(const float4*)(xrow + ks * 32);
            float4 f1 = *(const float4*)(xrow + ks * 32 + 4);
            unsigned short u[8] = { f2b(f0.x), f2b(f0.y), f2b(f0.z), f2b(f0.w),
                                    f2b(f1.x), f2b(f1.y), f2b(f1.z), f2b(f1.w) };
            *(s8v*)&As[(sg * 64 + srow) * 8] = *(const s8v*)u;
        }
#pragma unroll
        for (int it = 0; it < 4; ++it) {
            int c = t + it * 256;
            int g = c & 3, n = c >> 2;
            *(s8v*)&Bs[(g * 256 + n) * 8] = *(const s8v*)&Wt[(size_t)n * 128 + ks * 32 + g * 8];
        }
        __syncthreads();
        s8v af[4], bf[4];
#pragma unroll
        for (int rf = 0; rf < 4; ++rf) af[rf] = *(const s8v*)&As[(lq * 64 + rf * 16 + lr) * 8];
#pragma unroll
        for (int cf = 0; cf < 4; ++cf) bf[cf] = *(const s8v*)&Bs[(lq * 256 + w * 64 + cf * 16 + lr) * 8];
#pragma unroll
        for (int rf = 0; rf < 4; ++rf)
#pragma unroll
            for (int cf = 0; cf < 4; ++cf)
                acc[rf][cf] = __builtin_amdgcn_mfma_f32_16x16x32_bf16(af[rf], bf[cf], acc[rf][cf], 0, 0, 0);
        __syncthreads();
    }
#pragma unroll
    for (int cf = 0; cf < 4; ++cf) {
        int c = w * 64 + cf * 16 + lr;
#pragma unroll
        for (int rf = 0; rf < 4; ++rf)
#pragma unroll
            for (int i = 0; i < 4; ++i) {
                int row = rf * 16 + lq * 4 + i;
                Hs[((c >> 3) * 64 + row) * 8 + (c & 7)] = f2b(acc[rf][cf][i]);
            }
    }
    __syncthreads();
    // flush interleaved: hc[node*128 + fp*2] = {loc pair}, +1 = {reg pair}
#pragma unroll
    for (int it = 0; it < 16; ++it) {
        int idx = t + it * 256;           // 64 rows x 64 feature-pairs
        int row = idx >> 6, fp = idx & 63;
        int node = r0 + row;
        if (node < NN) {
            int c0 = 2 * fp;              // loc features 2fp,2fp+1
            int c1 = 128 + 2 * fp;        // reg features
            unsigned lo = *(const unsigned*)&Hs[((c0 >> 3) * 64 + row) * 8 + (c0 & 7)];
            unsigned hi = *(const unsigned*)&Hs[((c1 >> 3) * 64 + row) * 8 + (c1 & 7)];
            uint2 p; p.x = lo; p.y = hi;
            *(uint2*)&hc[(size_t)node * 128 + fp * 2] = p;
        }
    }
#pragma unroll
    for (int it = 0; it < 4; ++it) {
        int row = it * 16 + (t >> 4);
        int node = r0 + row;
        int q = t & 15;
        int gat = q >> 3, sd = (q >> 2) & 1, head = q & 3;
        const float* av = gat ? (sd ? reg_ad : reg_as) : (sd ? loc_ad : loc_as);
        float s = 0.f;
        int cbase = gat * 128 + head * 32;
        for (int d = 0; d < 32; ++d) {
            int c = cbase + d;
            s += b2f(Hs[((c >> 3) * 64 + row) * 8 + (c & 7)]) * av[head * 32 + d];
        }
        if (node < NN) {
            float* outp = gat ? (sd ? ald_r : als_r) : (sd ? ald_l : als_l);
            outp[(size_t)node * 4 + head] = s;
        }
    }
}

// ---------------- pooling ----------------
__global__ void k_pool(const float* __restrict__ x, const int* __restrict__ batch,
                       float* pooled) {
    int t = threadIdx.x;
    int f = t & 127, half = t >> 7;
    int rstart = blockIdx.x * 256;
    int rend = rstart + 256; if (rend > NN) rend = NN;
    float acc = 0.f; int cur_b = -1;
    for (int r = rstart + half; r < rend; r += 2) {
        int b = batch[r];
        if (b != cur_b) {
            if (cur_b >= 0) atomicAdd(&pooled[cur_b * 128 + f], acc);
            cur_b = b; acc = 0.f;
        }
        acc += x[r * 128 + f];
    }
    if (cur_b >= 0) atomicAdd(&pooled[cur_b * 128 + f], acc);
}

// ---------------- gfeat: one block per graph ----------------
__global__ __launch_bounds__(256) void k_gfeat8(
    const float* __restrict__ pooled, const int* __restrict__ batch,
    const float* __restrict__ W1, const float* __restrict__ b1,
    const float* __restrict__ W2, const float* __restrict__ b2,
    unsigned short* __restrict__ g8b) {
    __shared__ float mean_s[128];
    __shared__ float hid_s[128];
    __shared__ float part[256];
    __shared__ int bnd[2];
    int b = blockIdx.x, t = threadIdx.x;
    if (t < 2) {
        int target = b + t;
        int lo = 0, hi = NN;
        while (lo < hi) { int mid = (lo + hi) >> 1; if (batch[mid] < target) lo = mid + 1; else hi = mid; }
        bnd[t] = lo;
    }
    __syncthreads();
    int cnt = bnd[1] - bnd[0];
    float inv = cnt ? 1.f / (float)cnt : 0.f;
    if (t < 128) mean_s[t] = pooled[b * 128 + t] * inv;
    __syncthreads();
    int c = t & 127, kh = t >> 7;
    float a = 0.f;
    for (int k = kh * 64; k < kh * 64 + 64; k++) a += mean_s[k] * W1[k * 128 + c];
    part[t] = a;
    __syncthreads();
    if (t < 128) hid_s[t] = fmaxf(part[t] + part[t + 128] + b1[t], 0.f);
    __syncthreads();
    float a2 = 0.f;
    for (int k = kh * 64; k < kh * 64 + 64; k++) a2 += hid_s[k] * W2[k * 128 + c];
    part[t] = a2;
    __syncthreads();
    if (t < 128) g8b[b * 128 + t] = f2b(part[t] + part[t + 128] + b2[t]);
}

// ---------------- GAT aggregate v4: interleaved hc, 1 dwordx2 load per edge ----------------
__global__ __launch_bounds__(256) void k_gat(
    const int* __restrict__ row_ptr, const int* __restrict__ col,
    const unsigned* __restrict__ hc,
    const float* __restrict__ als_l, const float* __restrict__ ald_l,
    const float* __restrict__ als_r, const float* __restrict__ ald_r,
    const float* __restrict__ x,
    const float* __restrict__ loc_bias, const float* __restrict__ loc_g, const float* __restrict__ loc_b,
    const float* __restrict__ reg_bias, const float* __restrict__ reg_g, const float* __restrict__ reg_b,
    unsigned short* __restrict__ out_local, unsigned short* __restrict__ out_reg) {
    __shared__ float exC[4][64][8];   // [wave][edge][head*2 + {A,B}]
    __shared__ int   colb[4][64];
    __shared__ int   degs[4];
    int w = threadIdx.x >> 6, lane = threadIdx.x & 63;
    int hA = lane >> 4;                 // head of features {2*lane, 2*lane+1}
    int node = blockIdx.x * 4 + w;
    int rp0 = row_ptr[node];
    int deg = row_ptr[node + 1] - rp0;
    if (lane == 0) degs[w] = deg;
    float4 adL = *(const float4*)&ald_l[(size_t)node * 4];
    float4 adR = *(const float4*)&ald_r[(size_t)node * 4];
    __syncthreads();
    int maxdeg = max(max(degs[0], degs[1]), max(degs[2], degs[3]));
    int chunks = (maxdeg + 63) >> 6;

    // sweep: lane-parallel exp + sums (LDS stage valid for serial use iff chunks==1)
    float sL0 = 0.f, sL1 = 0.f, sL2 = 0.f, sL3 = 0.f;
    float sR0 = 0.f, sR1 = 0.f, sR2 = 0.f, sR3 = 0.f;
    for (int base = 0; base < deg; base += 64) {
        int i = base + lane;
        bool v = i < deg;
        int s = col[rp0 + (v ? i : deg - 1)];
        float4 aL = *(const float4*)&als_l[(size_t)s * 4];
        float4 aR = *(const float4*)&als_r[(size_t)s * 4];
        float e0 = __expf(lrelu(aL.x + adL.x));
        float e1 = __expf(lrelu(aL.y + adL.y));
        float e2 = __expf(lrelu(aL.z + adL.z));
        float e3 = __expf(lrelu(aL.w + adL.w));
        float f0 = __expf(lrelu(aR.x + adR.x));
        float f1 = __expf(lrelu(aR.y + adR.y));
        float f2 = __expf(lrelu(aR.z + adR.z));
        float f3 = __expf(lrelu(aR.w + adR.w));
        if (!v) { e0 = e1 = e2 = e3 = f0 = f1 = f2 = f3 = 0.f; }
        *(float4*)&exC[w][lane][0] = make_float4(e0, f0, e1, f1);
        *(float4*)&exC[w][lane][4] = make_float4(e2, f2, e3, f3);
        colb[w][lane] = s;
        sL0 += e0; sL1 += e1; sL2 += e2; sL3 += e3;
        sR0 += f0; sR1 += f1; sR2 += f2; sR3 += f3;
    }
    __syncthreads();
#pragma unroll
    for (int off = 32; off; off >>= 1) {
        sL0 += __shfl_xor(sL0, off); sL1 += __shfl_xor(sL1, off);
        sL2 += __shfl_xor(sL2, off); sL3 += __shfl_xor(sL3, off);
        sR0 += __shfl_xor(sR0, off); sR1 += __shfl_xor(sR1, off);
        sR2 += __shfl_xor(sR2, off); sR3 += __shfl_xor(sR3, off);
    }
    float iA = (hA & 2) ? ((hA & 1) ? 1.f / sL3 : 1.f / sL2)
                        : ((hA & 1) ? 1.f / sL1 : 1.f / sL0);
    float iB = (hA & 2) ? ((hA & 1) ? 1.f / sR3 : 1.f / sR2)
                        : ((hA & 1) ? 1.f / sR1 : 1.f / sR0);

    float a0 = 0.f, a1 = 0.f, b0 = 0.f, b1 = 0.f;
    const uint2* hcp = (const uint2*)hc;   // 8B units: node*64 + lane
    if (chunks == 1) {
#pragma unroll 8
        for (int e = 0; e < deg; ++e) {
            int s = colb[w][e];
            float2 ex = *(const float2*)&exC[w][e][hA * 2];
            uint2 u = hcp[(size_t)s * 64 + lane];
            a0 += ex.x * uasf(u.x << 16);
            a1 += ex.x * uasf(u.x & 0xffff0000u);
            b0 += ex.y * uasf(u.y << 16);
            b1 += ex.y * uasf(u.y & 0xffff0000u);
        }
    } else {
        for (int c = 0; c < chunks; ++c) {
            int base = c * 64, i = base + lane;
            if (i < deg) {
                int s = col[rp0 + i];
                float4 aL = *(const float4*)&als_l[(size_t)s * 4];
                float4 aR = *(const float4*)&als_r[(size_t)s * 4];
                *(float4*)&exC[w][lane][0] = make_float4(
                    __expf(lrelu(aL.x + adL.x)), __expf(lrelu(aR.x + adR.x)),
                    __expf(lrelu(aL.y + adL.y)), __expf(lrelu(aR.y + adR.y)));
                *(float4*)&exC[w][lane][4] = make_float4(
                    __expf(lrelu(aL.z + adL.z)), __expf(lrelu(aR.z + adR.z)),
                    __expf(lrelu(aL.w + adL.w)), __expf(lrelu(aR.w + adR.w)));
                colb[w][lane] = s;
            }
            __syncthreads();
            int nc = deg - base; nc = nc < 0 ? 0 : (nc > 64 ? 64 : nc);
#pragma unroll 8
            for (int e = 0; e < nc; ++e) {
                int s = colb[w][e];
                float2 ex = *(const float2*)&exC[w][e][hA * 2];
                uint2 u = hcp[(size_t)s * 64 + lane];
                a0 += ex.x * uasf(u.x << 16);
                a1 += ex.x * uasf(u.x & 0xffff0000u);
                b0 += ex.y * uasf(u.y << 16);
                b1 += ex.y * uasf(u.y & 0xffff0000u);
            }
            __syncthreads();
        }
    }

    // epilogue: bias + residual + LN (features 2*lane, 2*lane+1)
    int f = 2 * lane;
    float2 xr = *(const float2*)&x[(size_t)node * 128 + f];
    float2 lbi = *(const float2*)&loc_bias[f];
    float2 rbi = *(const float2*)&reg_bias[f];
    float v0 = a0 * iA + lbi.x + xr.x;
    float v1 = a1 * iA + lbi.y + xr.y;
    float u0 = b0 * iB + rbi.x + xr.x;
    float u1 = b1 * iB + rbi.y + xr.y;

    float sv = v0 + v1, su = u0 + u1;
#pragma unroll
    for (int off = 32; off; off >>= 1) { sv += __shfl_xor(sv, off); su += __shfl_xor(su, off); }
    float mv = sv * (1.f / 128.f), mu = su * (1.f / 128.f);
    float dv0 = v0 - mv, dv1 = v1 - mv, du0 = u0 - mu, du1 = u1 - mu;
    float qv = dv0 * dv0 + dv1 * dv1, qu = du0 * du0 + du1 * du1;
#pragma unroll
    for (int off = 32; off; off >>= 1) { qv += __shfl_xor(qv, off); qu += __shfl_xor(qu, off); }
    float rv = rsqrtf(qv * (1.f / 128.f) + 1e-5f), ru = rsqrtf(qu * (1.f / 128.f) + 1e-5f);
    float2 lg = *(const float2*)&loc_g[f], lb2 = *(const float2*)&loc_b[f];
    float2 rg = *(const float2*)&reg_g[f], rb2 = *(const float2*)&reg_b[f];
    unsigned pv = (unsigned)f2b(dv0 * rv * lg.x + lb2.x) | ((unsigned)f2b(dv1 * rv * lg.y + lb2.y) << 16);
    unsigned pu = (unsigned)f2b(du0 * ru * rg.x + rb2.x) | ((unsigned)f2b(du1 * ru * rg.y + rb2.y) << 16);
    *(unsigned*)&out_local[(size_t)node * 128 + f] = pv;
    *(unsigned*)&out_reg[(size_t)node * 128 + f]   = pu;
}

// ---------------- fused MLP (MFMA) ----------------
__global__ __launch_bounds__(256) void k_fusedm(
    const unsigned short* __restrict__ localb, const unsigned short* __restrict__ regionalb,
    const unsigned short* __restrict__ g8b, const int* __restrict__ batch,
    const unsigned short* __restrict__ W1t, const float* __restrict__ b1,
    const unsigned short* __restrict__ W2t, const float* __restrict__ b2,
    const float* __restrict__ lng, const float* __restrict__ lnb,
    float* __restrict__ out) {
    __shared__ unsigned short As[4 * 64 * 8];
    __shared__ unsigned short Bs[4 * 256 * 8];
    __shared__ unsigned short Hs[32 * 64 * 8];
    __shared__ unsigned short W2s[4 * 128 * 8];
    int t = threadIdx.x;
    int w = t >> 6, l = t & 63;
    int lq = l >> 4, lr = l & 15;
    int r0 = blockIdx.x * 64;

    int srow = t >> 2, sg = t & 3;
    int snode = r0 + srow; if (snode >= NN) snode = NN - 1;
    int sbatch = batch[snode];

    f4v acc[4][4];
#pragma unroll
    for (int a0 = 0; a0 < 4; a0++)
#pragma unroll
        for (int b0 = 0; b0 < 4; b0++) acc[a0][b0] = (f4v){0.f, 0.f, 0.f, 0.f};

    for (int ks = 0; ks < 12; ++ks) {
        int seg = ks >> 2;
        int ko = (ks & 3) * 32 + sg * 8;
        const unsigned short* src =
            seg == 0 ? localb + (size_t)snode * 128 + ko :
            seg == 1 ? regionalb + (size_t)snode * 128 + ko :
                       g8b + (size_t)sbatch * 128 + ko;
        *(s8v*)&As[(sg * 64 + srow) * 8] = *(const s8v*)src;
#pragma unroll
        for (int it = 0; it < 4; ++it) {
            int c = t + it * 256;
            int g = c & 3, n = c >> 2;
            *(s8v*)&Bs[(g * 256 + n) * 8] = *(const s8v*)&W1t[(size_t)n * 384 + ks * 32 + g * 8];
        }
        __syncthreads();
        s8v af[4], bf[4];
#pragma unroll
        for (int rf = 0; rf < 4; ++rf) af[rf] = *(const s8v*)&As[(lq * 64 + rf * 16 + lr) * 8];
#pragma unroll
        for (int cf = 0; cf < 4; ++cf) bf[cf] = *(const s8v*)&Bs[(lq * 256 + w * 64 + cf * 16 + lr) * 8];
#pragma unroll
        for (int rf = 0; rf < 4; ++rf)
#pragma unroll
            for (int cf = 0; cf < 4; ++cf)
                acc[rf][cf] = __builtin_amdgcn_mfma_f32_16x16x32_bf16(af[rf], bf[cf], acc[rf][cf], 0, 0, 0);
        __syncthreads();
    }
#pragma unroll
    for (int cf = 0; cf < 4; ++cf) {
        int c = w * 64 + cf * 16 + lr;
        float bc = b1[c];
#pragma unroll
        for (int rf = 0; rf < 4; ++rf)
#pragma unroll
            for (int i = 0; i < 4; ++i) {
                int row = rf * 16 + lq * 4 + i;
                float v0 = acc[rf][cf][i] + bc;
                Hs[((c >> 3) * 64 + row) * 8 + (c & 7)] = f2b(v0 > 0.f ? v0 : 0.f);
            }
    }
    __syncthreads();
    f4v a2[8];
#pragma unroll
    for (int cf = 0; cf < 8; ++cf) a2[cf] = (f4v){0.f, 0.f, 0.f, 0.f};
    for (int ks = 0; ks < 8; ++ks) {
#pragma unroll
        for (int it = 0; it < 2; ++it) {
            int c = t + it * 256;
            int g = c & 3, n = c >> 2;
            *(s8v*)&W2s[(g * 128 + n) * 8] = *(const s8v*)&W2t[(size_t)n * 256 + ks * 32 + g * 8];
        }
        __syncthreads();
        s8v af = *(const s8v*)&Hs[((ks * 4 + lq) * 64 + w * 16 + lr) * 8];
#pragma unroll
        for (int cf = 0; cf < 8; ++cf) {
            s8v bfv = *(const s8v*)&W2s[(lq * 128 + cf * 16 + lr) * 8];
            a2[cf] = __builtin_amdgcn_mfma_f32_16x16x32_bf16(af, bfv, a2[cf], 0, 0, 0);
        }
        __syncthreads();
    }
    float b2c[8], gc[8], bc2[8];
#pragma unroll
    for (int cf = 0; cf < 8; ++cf) {
        int c = cf * 16 + lr;
        b2c[cf] = b2[c]; gc[cf] = lng[c]; bc2[cf] = lnb[c];
    }
#pragma unroll
    for (int i = 0; i < 4; ++i) {
        int row = w * 16 + lq * 4 + i;
        int node = r0 + row;
        float vals[8]; float s = 0.f;
#pragma unroll
        for (int cf = 0; cf < 8; ++cf) { vals[cf] = a2[cf][i] + b2c[cf]; s += vals[cf]; }
        s += __shfl_xor(s, 1); s += __shfl_xor(s, 2); s += __shfl_xor(s, 4); s += __shfl_xor(s, 8);
        float mean = s * (1.f / 128.f);
        float vs = 0.f;
#pragma unroll
        for (int cf = 0; cf < 8; ++cf) { float d = vals[cf] - mean; vs += d * d; }
        vs += __shfl_xor(vs, 1); vs += __shfl_xor(vs, 2); vs += __shfl_xor(vs, 4); vs += __shfl_xor(vs, 8);
        float rstd = rsqrtf(vs * (1.f / 128.f) + 1e-5f);
        if (node < NN) {
#pragma unroll
            for (int cf = 0; cf < 8; ++cf)
                out[(size_t)node * 128 + cf * 16 + lr] = (vals[cf] - mean) * rstd * gc[cf] + bc2[cf];
        }
    }
}

extern "C" void kernel_launch(void* const* d_in, const int* in_sizes, int n_in,
                              void* d_out, int out_size, void* d_ws, size_t ws_size,
                              hipStream_t stream) {
    const float* x      = (const float*)d_in[0];
    const int*   ei     = (const int*)d_in[1];
    const int*   batch  = (const int*)d_in[2];
    const float* locW   = (const float*)d_in[3];
    const float* loc_as = (const float*)d_in[4];
    const float* loc_ad = (const float*)d_in[5];
    const float* loc_bi = (const float*)d_in[6];
    const float* loc_g  = (const float*)d_in[7];
    const float* loc_b  = (const float*)d_in[8];
    const float* regW   = (const float*)d_in[9];
    const float* reg_as = (const float*)d_in[10];
    const float* reg_ad = (const float*)d_in[11];
    const float* reg_bi = (const float*)d_in[12];
    const float* reg_g  = (const float*)d_in[13];
    const float* reg_b  = (const float*)d_in[14];
    const float* gp_W1  = (const float*)d_in[15];
    const float* gp_b1  = (const float*)d_in[16];
    const float* gp_W2  = (const float*)d_in[17];
    const float* gp_b2  = (const float*)d_in[18];
    const float* fu_W1  = (const float*)d_in[19];
    const float* fu_b1  = (const float*)d_in[20];
    const float* fu_W2  = (const float*)d_in[21];
    const float* fu_b2  = (const float*)d_in[22];
    const float* fu_lg  = (const float*)d_in[23];
    const float* fu_lb  = (const float*)d_in[24];
    float* out = (float*)d_out;

    char* ws = (char*)d_ws;
    size_t off = 0;
    auto alloc = [&](size_t bytes) { void* p = ws + off; off += (bytes + 255) & ~(size_t)255; return p; };
    unsigned* hc              = (unsigned*)alloc((size_t)NN * 128 * 4);
    unsigned short* localb    = (unsigned short*)alloc((size_t)NN * 128 * 2);
    unsigned short* regionalb = (unsigned short*)alloc((size_t)NN * 128 * 2);
    float* als_l  = (float*)alloc((size_t)NN * 4 * 4);
    float* ald_l  = (float*)alloc((size_t)NN * 4 * 4);
    float* als_r  = (float*)alloc((size_t)NN * 4 * 4);
    float* ald_r  = (float*)alloc((size_t)NN * 4 * 4);
    int* row_ptr  = (int*)alloc((size_t)(NN + 1) * 4);
    int* cur      = (int*)alloc((size_t)NN * 4);
    int* col      = (int*)alloc((size_t)(EE + NN) * 4);
    float* pooled = (float*)alloc((size_t)BB * 128 * 4);
    unsigned short* g8b = (unsigned short*)alloc((size_t)BB * 128 * 2);
    unsigned short* Wt  = (unsigned short*)alloc((size_t)32768 * 2);
    unsigned short* W1t = (unsigned short*)alloc((size_t)98304 * 2);
    unsigned short* W2t = (unsigned short*)alloc((size_t)32768 * 2);
    int* bsum = (int*)alloc((size_t)NBLK * 4);
    int* boff = (int*)alloc((size_t)NBLK * 4);

    hipLaunchKernelGGL(k_init, dim3((NN + 255) / 256), dim3(256), 0, stream, cur, pooled);
    hipLaunchKernelGGL(k_count, dim3((EE + 255) / 256), dim3(256), 0, stream, ei, cur);
    hipLaunchKernelGGL(k_scanA, dim3(NBLK), dim3(256), 0, stream, cur, row_ptr, bsum);
    hipLaunchKernelGGL(k_scanB, dim3(1), dim3(256), 0, stream, bsum, boff);
    hipLaunchKernelGGL(k_scanC, dim3(NBLK), dim3(256), 0, stream, row_ptr, boff);
    hipLaunchKernelGGL(k_scatter, dim3((EE + NN + 255) / 256), dim3(256), 0, stream, ei, row_ptr, cur, col);
    hipLaunchKernelGGL(k_convw, dim3(640), dim3(256), 0, stream,
                       locW, regW, fu_W1, fu_W2, Wt, W1t, W2t);
    hipLaunchKernelGGL(k_gemm1, dim3((NN + 63) / 64), dim3(256), 0, stream,
                       x, Wt, loc_as, loc_ad, reg_as, reg_ad,
                       hc, als_l, ald_l, als_r, ald_r);
    hipLaunchKernelGGL(k_pool, dim3((NN + 255) / 256), dim3(256), 0, stream, x, batch, pooled);
    hipLaunchKernelGGL(k_gfeat8, dim3(BB), dim3(256), 0, stream,
                       pooled, batch, gp_W1, gp_b1, gp_W2, gp_b2, g8b);
    hipLaunchKernelGGL(k_gat, dim3(NN / 4), dim3(256), 0, stream,
                       row_ptr, col, hc, als_l, ald_l, als_r, ald_r, x,
                       loc_bi, loc_g, loc_b, reg_bi, reg_g, reg_b,
                       localb, regionalb);
    hipLaunchKernelGGL(k_fusedm, dim3((NN + 63) / 64), dim3(256), 0, stream,
                       localb, regionalb, g8b, batch,
                       W1t, fu_b1, W2t, fu_b2, fu_lg, fu_lb, out);
}

// Round 7
// 311.714 us; speedup vs baseline: 1.0165x; 1.0165x over previous
//
#include <hip/hip_runtime.h>

#define NN 50000
#define EE 800000
#define FF 128
#define HH 4
#define BB 8
#define NEG 0.2f
#define NBLK ((NN + 255) / 256)   // 196

typedef __attribute__((ext_vector_type(8))) short s8v;
typedef __attribute__((ext_vector_type(4))) float f4v;

__device__ __forceinline__ unsigned short f2b(float f) {
    union { float f; unsigned u; } v; v.f = f;
    unsigned r = v.u + 0x7fffu + ((v.u >> 16) & 1u);
    return (unsigned short)(r >> 16);
}
__device__ __forceinline__ float b2f(unsigned short h) {
    union { unsigned u; float f; } v; v.u = ((unsigned)h) << 16;
    return v.f;
}
__device__ __forceinline__ float uasf(unsigned u) {
    union { unsigned u; float f; } v; v.u = u; return v.f;
}
__device__ __forceinline__ float lrelu(float t) { return t > 0.f ? t : NEG * t; }

// ---------------- init: cur=1 (self loop), pooled=0 ----------------
__global__ void k_init(int* cur, float* pooled) {
    int i = blockIdx.x * 256 + threadIdx.x;
    if (i < NN) cur[i] = 1;
    if (i < BB * FF) pooled[i] = 0.f;
}

// ---------------- count in-degree ----------------
__global__ void k_count(const int* __restrict__ ei, int* cur) {
    int i = blockIdx.x * 256 + threadIdx.x;
    if (i < EE) atomicAdd(&cur[ei[EE + i]], 1);
}

// ---------------- 3-phase parallel scan ----------------
__global__ __launch_bounds__(256) void k_scanA(int* cur, int* row_ptr, int* bsum) {
    __shared__ int wsum[4];
    int b = blockIdx.x, t = threadIdx.x;
    int i = b * 256 + t;
    int v = (i < NN) ? cur[i] : 0;
    if (i < NN) cur[i] = 0;
    int lane = t & 63, w = t >> 6;
    int sc = v;
#pragma unroll
    for (int off = 1; off < 64; off <<= 1) {
        int n = __shfl_up(sc, off);
        if (lane >= off) sc += n;
    }
    if (lane == 63) wsum[w] = sc;
    __syncthreads();
    int woff = 0;
    for (int k = 0; k < w; k++) woff += wsum[k];
    int incl = sc + woff;
    if (i < NN) row_ptr[i + 1] = incl;
    if (t == 255) bsum[b] = incl;
    if (i == 0) row_ptr[0] = 0;
}

__global__ __launch_bounds__(256) void k_scanB(const int* __restrict__ bsum, int* boff) {
    __shared__ int wsum[4];
    int t = threadIdx.x;
    int v = (t < NBLK) ? bsum[t] : 0;
    int lane = t & 63, w = t >> 6;
    int sc = v;
#pragma unroll
    for (int off = 1; off < 64; off <<= 1) {
        int n = __shfl_up(sc, off);
        if (lane >= off) sc += n;
    }
    if (lane == 63) wsum[w] = sc;
    __syncthreads();
    int woff = 0;
    for (int k = 0; k < w; k++) woff += wsum[k];
    if (t < NBLK) boff[t] = sc + woff - v;
}

__global__ __launch_bounds__(256) void k_scanC(int* row_ptr, const int* __restrict__ boff) {
    int i = blockIdx.x * 256 + threadIdx.x;
    if (i < NN) row_ptr[i + 1] += boff[blockIdx.x];
}

// ---------------- scatter edges (and self loops) into CSR ----------------
__global__ void k_scatter(const int* __restrict__ ei, const int* __restrict__ row_ptr,
                          int* cur, int* col) {
    int i = blockIdx.x * 256 + threadIdx.x;
    if (i < EE) {
        int s = ei[i], d = ei[EE + i];
        int p = atomicAdd(&cur[d], 1);
        col[row_ptr[d] + p] = s;
    } else if (i < EE + NN) {
        int n = i - EE;
        int p = atomicAdd(&cur[n], 1);
        col[row_ptr[n] + p] = n;
    }
}

// ---------------- weight transpose+convert to bf16 ----------------
__global__ void k_convw(const float* __restrict__ locW, const float* __restrict__ regW,
                        const float* __restrict__ W1, const float* __restrict__ W2,
                        unsigned short* __restrict__ Wt, unsigned short* __restrict__ W1t,
                        unsigned short* __restrict__ W2t) {
    int i = blockIdx.x * 256 + threadIdx.x;
    if (i < 32768) {
        int n = i >> 7, k = i & 127;
        float v = n < 128 ? locW[k * 128 + n] : regW[k * 128 + n - 128];
        Wt[i] = f2b(v);
    } else if (i < 32768 + 98304) {
        int j = i - 32768; int n = j / 384, k = j - n * 384;
        W1t[j] = f2b(W1[k * 256 + n]);
    } else if (i < 163840) {
        int j = i - 131072; int n = j >> 8, k = j & 255;
        W2t[j] = f2b(W2[k * 128 + n]);
    }
}

// ---------------- GEMM1 (MFMA): h = bf16(x) @ W -> interleaved hc; alpha epilogue ----------------
__global__ __launch_bounds__(256) void k_gemm1(
    const float* __restrict__ x,
    const unsigned short* __restrict__ Wt,
    const float* __restrict__ loc_as, const float* __restrict__ loc_ad,
    const float* __restrict__ reg_as, const float* __restrict__ reg_ad,
    unsigned* __restrict__ hc,
    float* __restrict__ als_l, float* __restrict__ ald_l,
    float* __restrict__ als_r, float* __restrict__ ald_r) {
    __shared__ unsigned short As[4 * 64 * 8];
    __shared__ unsigned short Bs[4 * 256 * 8];
    __shared__ unsigned short Hs[32 * 64 * 8];
    int t = threadIdx.x;
    int w = t >> 6, l = t & 63;
    int lq = l >> 4, lr = l & 15;
    int r0 = blockIdx.x * 64;

    int srow = t >> 2, sg = t & 3;
    int snode = r0 + srow; if (snode >= NN) snode = NN - 1;
    const float* xrow = x + (size_t)snode * 128 + sg * 8;

    f4v acc[4][4];
#pragma unroll
    for (int a0 = 0; a0 < 4; a0++)
#pragma unroll
        for (int b0 = 0; b0 < 4; b0++) acc[a0][b0] = (f4v){0.f, 0.f, 0.f, 0.f};

    for (int ks = 0; ks < 4; ++ks) {
        {
            float4 f0 = *(const float4*)(xrow + ks * 32);
            float4 f1 = *(const float4*)(xrow + ks * 32 + 4);
            unsigned short u[8] = { f2b(f0.x), f2b(f0.y), f2b(f0.z), f2b(f0.w),
                                    f2b(f1.x), f2b(f1.y), f2b(f1.z), f2b(f1.w) };
            *(s8v*)&As[(sg * 64 + srow) * 8] = *(const s8v*)u;
        }
#pragma unroll
        for (int it = 0; it < 4; ++it) {
            int c = t + it * 256;
            int g = c & 3, n = c >> 2;
            *(s8v*)&Bs[(g * 256 + n) * 8] = *(const s8v*)&Wt[(size_t)n * 128 + ks * 32 + g * 8];
        }
        __syncthreads();
        s8v af[4], bf[4];
#pragma unroll
        for (int rf = 0; rf < 4; ++rf) af[rf] = *(const s8v*)&As[(lq * 64 + rf * 16 + lr) * 8];
#pragma unroll
        for (int cf = 0; cf < 4; ++cf) bf[cf] = *(const s8v*)&Bs[(lq * 256 + w * 64 + cf * 16 + lr) * 8];
#pragma unroll
        for (int rf = 0; rf < 4; ++rf)
#pragma unroll
            for (int cf = 0; cf < 4; ++cf)
                acc[rf][cf] = __builtin_amdgcn_mfma_f32_16x16x32_bf16(af[rf], bf[cf], acc[rf][cf], 0, 0, 0);
        __syncthreads();
    }
#pragma unroll
    for (int cf = 0; cf < 4; ++cf) {
        int c = w * 64 + cf * 16 + lr;
#pragma unroll
        for (int rf = 0; rf < 4; ++rf)
#pragma unroll
            for (int i = 0; i < 4; ++i) {
                int row = rf * 16 + lq * 4 + i;
                Hs[((c >> 3) * 64 + row) * 8 + (c & 7)] = f2b(acc[rf][cf][i]);
            }
    }
    __syncthreads();
    // flush interleaved: hc[node*128 + fp*2] = {loc pair}, +1 = {reg pair}
#pragma unroll
    for (int it = 0; it < 16; ++it) {
        int idx = t + it * 256;           // 64 rows x 64 feature-pairs
        int row = idx >> 6, fp = idx & 63;
        int node = r0 + row;
        if (node < NN) {
            int c0 = 2 * fp;
            int c1 = 128 + 2 * fp;
            unsigned lo = *(const unsigned*)&Hs[((c0 >> 3) * 64 + row) * 8 + (c0 & 7)];
            unsigned hi = *(const unsigned*)&Hs[((c1 >> 3) * 64 + row) * 8 + (c1 & 7)];
            uint2 p; p.x = lo; p.y = hi;
            *(uint2*)&hc[(size_t)node * 128 + fp * 2] = p;
        }
    }
#pragma unroll
    for (int it = 0; it < 4; ++it) {
        int row = it * 16 + (t >> 4);
        int node = r0 + row;
        int q = t & 15;
        int gat = q >> 3, sd = (q >> 2) & 1, head = q & 3;
        const float* av = gat ? (sd ? reg_ad : reg_as) : (sd ? loc_ad : loc_as);
        float s = 0.f;
        int cbase = gat * 128 + head * 32;
        for (int d = 0; d < 32; ++d) {
            int c = cbase + d;
            s += b2f(Hs[((c >> 3) * 64 + row) * 8 + (c & 7)]) * av[head * 32 + d];
        }
        if (node < NN) {
            float* outp = gat ? (sd ? ald_r : als_r) : (sd ? ald_l : als_l);
            outp[(size_t)node * 4 + head] = s;
        }
    }
}

// ---------------- pooling ----------------
__global__ void k_pool(const float* __restrict__ x, const int* __restrict__ batch,
                       float* pooled) {
    int t = threadIdx.x;
    int f = t & 127, half = t >> 7;
    int rstart = blockIdx.x * 256;
    int rend = rstart + 256; if (rend > NN) rend = NN;
    float acc = 0.f; int cur_b = -1;
    for (int r = rstart + half; r < rend; r += 2) {
        int b = batch[r];
        if (b != cur_b) {
            if (cur_b >= 0) atomicAdd(&pooled[cur_b * 128 + f], acc);
            cur_b = b; acc = 0.f;
        }
        acc += x[r * 128 + f];
    }
    if (cur_b >= 0) atomicAdd(&pooled[cur_b * 128 + f], acc);
}

// ---------------- gfeat: one block per graph ----------------
__global__ __launch_bounds__(256) void k_gfeat8(
    const float* __restrict__ pooled, const int* __restrict__ batch,
    const float* __restrict__ W1, const float* __restrict__ b1,
    const float* __restrict__ W2, const float* __restrict__ b2,
    unsigned short* __restrict__ g8b) {
    __shared__ float mean_s[128];
    __shared__ float hid_s[128];
    __shared__ float part[256];
    __shared__ int bnd[2];
    int b = blockIdx.x, t = threadIdx.x;
    if (t < 2) {
        int target = b + t;
        int lo = 0, hi = NN;
        while (lo < hi) { int mid = (lo + hi) >> 1; if (batch[mid] < target) lo = mid + 1; else hi = mid; }
        bnd[t] = lo;
    }
    __syncthreads();
    int cnt = bnd[1] - bnd[0];
    float inv = cnt ? 1.f / (float)cnt : 0.f;
    if (t < 128) mean_s[t] = pooled[b * 128 + t] * inv;
    __syncthreads();
    int c = t & 127, kh = t >> 7;
    float a = 0.f;
    for (int k = kh * 64; k < kh * 64 + 64; k++) a += mean_s[k] * W1[k * 128 + c];
    part[t] = a;
    __syncthreads();
    if (t < 128) hid_s[t] = fmaxf(part[t] + part[t + 128] + b1[t], 0.f);
    __syncthreads();
    float a2 = 0.f;
    for (int k = kh * 64; k < kh * 64 + 64; k++) a2 += hid_s[k] * W2[k * 128 + c];
    part[t] = a2;
    __syncthreads();
    if (t < 128) g8b[b * 128 + t] = f2b(part[t] + part[t + 128] + b2[t]);
}

// ---------------- GAT aggregate v5: interleaved hc single load + conflict-free exA/exB ----------------
__global__ __launch_bounds__(256) void k_gat(
    const int* __restrict__ row_ptr, const int* __restrict__ col,
    const unsigned* __restrict__ hc,
    const float* __restrict__ als_l, const float* __restrict__ ald_l,
    const float* __restrict__ als_r, const float* __restrict__ ald_r,
    const float* __restrict__ x,
    const float* __restrict__ loc_bias, const float* __restrict__ loc_g, const float* __restrict__ loc_b,
    const float* __restrict__ reg_bias, const float* __restrict__ reg_g, const float* __restrict__ reg_b,
    unsigned short* __restrict__ out_local, unsigned short* __restrict__ out_reg) {
    __shared__ float exA[4][64][4];
    __shared__ float exB[4][64][4];
    __shared__ int   colb[4][64];
    __shared__ int   degs[4];
    int w = threadIdx.x >> 6, lane = threadIdx.x & 63;
    int hA = lane >> 4;                 // head of features {2*lane, 2*lane+1}
    int node = blockIdx.x * 4 + w;
    int rp0 = row_ptr[node];
    int deg = row_ptr[node + 1] - rp0;
    if (lane == 0) degs[w] = deg;
    float4 adL = *(const float4*)&ald_l[(size_t)node * 4];
    float4 adR = *(const float4*)&ald_r[(size_t)node * 4];
    __syncthreads();
    int maxdeg = max(max(degs[0], degs[1]), max(degs[2], degs[3]));
    int chunks = (maxdeg + 63) >> 6;

    // sweep: lane-parallel exp + sums (LDS stage valid for serial use iff chunks==1)
    float sL0 = 0.f, sL1 = 0.f, sL2 = 0.f, sL3 = 0.f;
    float sR0 = 0.f, sR1 = 0.f, sR2 = 0.f, sR3 = 0.f;
    for (int base = 0; base < deg; base += 64) {
        int i = base + lane;
        bool v = i < deg;
        int s = col[rp0 + (v ? i : deg - 1)];
        float4 aL = *(const float4*)&als_l[(size_t)s * 4];
        float4 aR = *(const float4*)&als_r[(size_t)s * 4];
        float e0 = __expf(lrelu(aL.x + adL.x));
        float e1 = __expf(lrelu(aL.y + adL.y));
        float e2 = __expf(lrelu(aL.z + adL.z));
        float e3 = __expf(lrelu(aL.w + adL.w));
        float f0 = __expf(lrelu(aR.x + adR.x));
        float f1 = __expf(lrelu(aR.y + adR.y));
        float f2 = __expf(lrelu(aR.z + adR.z));
        float f3 = __expf(lrelu(aR.w + adR.w));
        if (!v) { e0 = e1 = e2 = e3 = f0 = f1 = f2 = f3 = 0.f; }
        *(float4*)&exA[w][lane][0] = make_float4(e0, e1, e2, e3);
        *(float4*)&exB[w][lane][0] = make_float4(f0, f1, f2, f3);
        colb[w][lane] = s;
        sL0 += e0; sL1 += e1; sL2 += e2; sL3 += e3;
        sR0 += f0; sR1 += f1; sR2 += f2; sR3 += f3;
    }
    __syncthreads();
#pragma unroll
    for (int off = 32; off; off >>= 1) {
        sL0 += __shfl_xor(sL0, off); sL1 += __shfl_xor(sL1, off);
        sL2 += __shfl_xor(sL2, off); sL3 += __shfl_xor(sL3, off);
        sR0 += __shfl_xor(sR0, off); sR1 += __shfl_xor(sR1, off);
        sR2 += __shfl_xor(sR2, off); sR3 += __shfl_xor(sR3, off);
    }
    float iA = (hA & 2) ? ((hA & 1) ? 1.f / sL3 : 1.f / sL2)
                        : ((hA & 1) ? 1.f / sL1 : 1.f / sL0);
    float iB = (hA & 2) ? ((hA & 1) ? 1.f / sR3 : 1.f / sR2)
                        : ((hA & 1) ? 1.f / sR1 : 1.f / sR0);

    float a0 = 0.f, a1 = 0.f, b0 = 0.f, b1 = 0.f;
    const uint2* hcp = (const uint2*)hc;   // 8B units: node*64 + lane
    if (chunks == 1) {
#pragma unroll 4
        for (int e = 0; e < deg; ++e) {
            int s = colb[w][e];
            float eAv = exA[w][e][hA];
            float eBv = exB[w][e][hA];
            uint2 u = hcp[(size_t)s * 64 + lane];
            a0 += eAv * uasf(u.x << 16);
            a1 += eAv * uasf(u.x & 0xffff0000u);
            b0 += eBv * uasf(u.y << 16);
            b1 += eBv * uasf(u.y & 0xffff0000u);
        }
    } else {
        for (int c = 0; c < chunks; ++c) {
            int base = c * 64, i = base + lane;
            if (i < deg) {
                int s = col[rp0 + i];
                float4 aL = *(const float4*)&als_l[(size_t)s * 4];
                float4 aR = *(const float4*)&als_r[(size_t)s * 4];
                *(float4*)&exA[w][lane][0] = make_float4(
                    __expf(lrelu(aL.x + adL.x)), __expf(lrelu(aL.y + adL.y)),
                    __expf(lrelu(aL.z + adL.z)), __expf(lrelu(aL.w + adL.w)));
                *(float4*)&exB[w][lane][0] = make_float4(
                    __expf(lrelu(aR.x + adR.x)), __expf(lrelu(aR.y + adR.y)),
                    __expf(lrelu(aR.z + adR.z)), __expf(lrelu(aR.w + adR.w)));
                colb[w][lane] = s;
            }
            __syncthreads();
            int nc = deg - base; nc = nc < 0 ? 0 : (nc > 64 ? 64 : nc);
#pragma unroll 4
            for (int e = 0; e < nc; ++e) {
                int s = colb[w][e];
                float eAv = exA[w][e][hA];
                float eBv = exB[w][e][hA];
                uint2 u = hcp[(size_t)s * 64 + lane];
                a0 += eAv * uasf(u.x << 16);
                a1 += eAv * uasf(u.x & 0xffff0000u);
                b0 += eBv * uasf(u.y << 16);
                b1 += eBv * uasf(u.y & 0xffff0000u);
            }
            __syncthreads();
        }
    }

    // epilogue: bias + residual + LN (features 2*lane, 2*lane+1)
    int f = 2 * lane;
    float2 xr = *(const float2*)&x[(size_t)node * 128 + f];
    float2 lbi = *(const float2*)&loc_bias[f];
    float2 rbi = *(const float2*)&reg_bias[f];
    float v0 = a0 * iA + lbi.x + xr.x;
    float v1 = a1 * iA + lbi.y + xr.y;
    float u0 = b0 * iB + rbi.x + xr.x;
    float u1 = b1 * iB + rbi.y + xr.y;

    float sv = v0 + v1, su = u0 + u1;
#pragma unroll
    for (int off = 32; off; off >>= 1) { sv += __shfl_xor(sv, off); su += __shfl_xor(su, off); }
    float mv = sv * (1.f / 128.f), mu = su * (1.f / 128.f);
    float dv0 = v0 - mv, dv1 = v1 - mv, du0 = u0 - mu, du1 = u1 - mu;
    float qv = dv0 * dv0 + dv1 * dv1, qu = du0 * du0 + du1 * du1;
#pragma unroll
    for (int off = 32; off; off >>= 1) { qv += __shfl_xor(qv, off); qu += __shfl_xor(qu, off); }
    float rv = rsqrtf(qv * (1.f / 128.f) + 1e-5f), ru = rsqrtf(qu * (1.f / 128.f) + 1e-5f);
    float2 lg = *(const float2*)&loc_g[f], lb2 = *(const float2*)&loc_b[f];
    float2 rg = *(const float2*)&reg_g[f], rb2 = *(const float2*)&reg_b[f];
    unsigned pv = (unsigned)f2b(dv0 * rv * lg.x + lb2.x) | ((unsigned)f2b(dv1 * rv * lg.y + lb2.y) << 16);
    unsigned pu = (unsigned)f2b(du0 * ru * rg.x + rb2.x) | ((unsigned)f2b(du1 * ru * rg.y + rb2.y) << 16);
    *(unsigned*)&out_local[(size_t)node * 128 + f] = pv;
    *(unsigned*)&out_reg[(size_t)node * 128 + f]   = pu;
}

// ---------------- fused MLP (MFMA) ----------------
__global__ __launch_bounds__(256) void k_fusedm(
    const unsigned short* __restrict__ localb, const unsigned short* __restrict__ regionalb,
    const unsigned short* __restrict__ g8b, const int* __restrict__ batch,
    const unsigned short* __restrict__ W1t, const float* __restrict__ b1,
    const unsigned short* __restrict__ W2t, const float* __restrict__ b2,
    const float* __restrict__ lng, const float* __restrict__ lnb,
    float* __restrict__ out) {
    __shared__ unsigned short As[4 * 64 * 8];
    __shared__ unsigned short Bs[4 * 256 * 8];
    __shared__ unsigned short Hs[32 * 64 * 8];
    __shared__ unsigned short W2s[4 * 128 * 8];
    int t = threadIdx.x;
    int w = t >> 6, l = t & 63;
    int lq = l >> 4, lr = l & 15;
    int r0 = blockIdx.x * 64;

    int srow = t >> 2, sg = t & 3;
    int snode = r0 + srow; if (snode >= NN) snode = NN - 1;
    int sbatch = batch[snode];

    f4v acc[4][4];
#pragma unroll
    for (int a0 = 0; a0 < 4; a0++)
#pragma unroll
        for (int b0 = 0; b0 < 4; b0++) acc[a0][b0] = (f4v){0.f, 0.f, 0.f, 0.f};

    for (int ks = 0; ks < 12; ++ks) {
        int seg = ks >> 2;
        int ko = (ks & 3) * 32 + sg * 8;
        const unsigned short* src =
            seg == 0 ? localb + (size_t)snode * 128 + ko :
            seg == 1 ? regionalb + (size_t)snode * 128 + ko :
                       g8b + (size_t)sbatch * 128 + ko;
        *(s8v*)&As[(sg * 64 + srow) * 8] = *(const s8v*)src;
#pragma unroll
        for (int it = 0; it < 4; ++it) {
            int c = t + it * 256;
            int g = c & 3, n = c >> 2;
            *(s8v*)&Bs[(g * 256 + n) * 8] = *(const s8v*)&W1t[(size_t)n * 384 + ks * 32 + g * 8];
        }
        __syncthreads();
        s8v af[4], bf[4];
#pragma unroll
        for (int rf = 0; rf < 4; ++rf) af[rf] = *(const s8v*)&As[(lq * 64 + rf * 16 + lr) * 8];
#pragma unroll
        for (int cf = 0; cf < 4; ++cf) bf[cf] = *(const s8v*)&Bs[(lq * 256 + w * 64 + cf * 16 + lr) * 8];
#pragma unroll
        for (int rf = 0; rf < 4; ++rf)
#pragma unroll
            for (int cf = 0; cf < 4; ++cf)
                acc[rf][cf] = __builtin_amdgcn_mfma_f32_16x16x32_bf16(af[rf], bf[cf], acc[rf][cf], 0, 0, 0);
        __syncthreads();
    }
#pragma unroll
    for (int cf = 0; cf < 4; ++cf) {
        int c = w * 64 + cf * 16 + lr;
        float bc = b1[c];
#pragma unroll
        for (int rf = 0; rf < 4; ++rf)
#pragma unroll
            for (int i = 0; i < 4; ++i) {
                int row = rf * 16 + lq * 4 + i;
                float v0 = acc[rf][cf][i] + bc;
                Hs[((c >> 3) * 64 + row) * 8 + (c & 7)] = f2b(v0 > 0.f ? v0 : 0.f);
            }
    }
    __syncthreads();
    f4v a2[8];
#pragma unroll
    for (int cf = 0; cf < 8; ++cf) a2[cf] = (f4v){0.f, 0.f, 0.f, 0.f};
    for (int ks = 0; ks < 8; ++ks) {
#pragma unroll
        for (int it = 0; it < 2; ++it) {
            int c = t + it * 256;
            int g = c & 3, n = c >> 2;
            *(s8v*)&W2s[(g * 128 + n) * 8] = *(const s8v*)&W2t[(size_t)n * 256 + ks * 32 + g * 8];
        }
        __syncthreads();
        s8v af = *(const s8v*)&Hs[((ks * 4 + lq) * 64 + w * 16 + lr) * 8];
#pragma unroll
        for (int cf = 0; cf < 8; ++cf) {
            s8v bfv = *(const s8v*)&W2s[(lq * 128 + cf * 16 + lr) * 8];
            a2[cf] = __builtin_amdgcn_mfma_f32_16x16x32_bf16(af, bfv, a2[cf], 0, 0, 0);
        }
        __syncthreads();
    }
    float b2c[8], gc[8], bc2[8];
#pragma unroll
    for (int cf = 0; cf < 8; ++cf) {
        int c = cf * 16 + lr;
        b2c[cf] = b2[c]; gc[cf] = lng[c]; bc2[cf] = lnb[c];
    }
#pragma unroll
    for (int i = 0; i < 4; ++i) {
        int row = w * 16 + lq * 4 + i;
        int node = r0 + row;
        float vals[8]; float s = 0.f;
#pragma unroll
        for (int cf = 0; cf < 8; ++cf) { vals[cf] = a2[cf][i] + b2c[cf]; s += vals[cf]; }
        s += __shfl_xor(s, 1); s += __shfl_xor(s, 2); s += __shfl_xor(s, 4); s += __shfl_xor(s, 8);
        float mean = s * (1.f / 128.f);
        float vs = 0.f;
#pragma unroll
        for (int cf = 0; cf < 8; ++cf) { float d = vals[cf] - mean; vs += d * d; }
        vs += __shfl_xor(vs, 1); vs += __shfl_xor(vs, 2); vs += __shfl_xor(vs, 4); vs += __shfl_xor(vs, 8);
        float rstd = rsqrtf(vs * (1.f / 128.f) + 1e-5f);
        if (node < NN) {
#pragma unroll
            for (int cf = 0; cf < 8; ++cf)
                out[(size_t)node * 128 + cf * 16 + lr] = (vals[cf] - mean) * rstd * gc[cf] + bc2[cf];
        }
    }
}

extern "C" void kernel_launch(void* const* d_in, const int* in_sizes, int n_in,
                              void* d_out, int out_size, void* d_ws, size_t ws_size,
                              hipStream_t stream) {
    const float* x      = (const float*)d_in[0];
    const int*   ei     = (const int*)d_in[1];
    const int*   batch  = (const int*)d_in[2];
    const float* locW   = (const float*)d_in[3];
    const float* loc_as = (const float*)d_in[4];
    const float* loc_ad = (const float*)d_in[5];
    const float* loc_bi = (const float*)d_in[6];
    const float* loc_g  = (const float*)d_in[7];
    const float* loc_b  = (const float*)d_in[8];
    const float* regW   = (const float*)d_in[9];
    const float* reg_as = (const float*)d_in[10];
    const float* reg_ad = (const float*)d_in[11];
    const float* reg_bi = (const float*)d_in[12];
    const float* reg_g  = (const float*)d_in[13];
    const float* reg_b  = (const float*)d_in[14];
    const float* gp_W1  = (const float*)d_in[15];
    const float* gp_b1  = (const float*)d_in[16];
    const float* gp_W2  = (const float*)d_in[17];
    const float* gp_b2  = (const float*)d_in[18];
    const float* fu_W1  = (const float*)d_in[19];
    const float* fu_b1  = (const float*)d_in[20];
    const float* fu_W2  = (const float*)d_in[21];
    const float* fu_b2  = (const float*)d_in[22];
    const float* fu_lg  = (const float*)d_in[23];
    const float* fu_lb  = (const float*)d_in[24];
    float* out = (float*)d_out;

    char* ws = (char*)d_ws;
    size_t off = 0;
    auto alloc = [&](size_t bytes) { void* p = ws + off; off += (bytes + 255) & ~(size_t)255; return p; };
    unsigned* hc              = (unsigned*)alloc((size_t)NN * 128 * 4);
    unsigned short* localb    = (unsigned short*)alloc((size_t)NN * 128 * 2);
    unsigned short* regionalb = (unsigned short*)alloc((size_t)NN * 128 * 2);
    float* als_l  = (float*)alloc((size_t)NN * 4 * 4);
    float* ald_l  = (float*)alloc((size_t)NN * 4 * 4);
    float* als_r  = (float*)alloc((size_t)NN * 4 * 4);
    float* ald_r  = (float*)alloc((size_t)NN * 4 * 4);
    int* row_ptr  = (int*)alloc((size_t)(NN + 1) * 4);
    int* cur      = (int*)alloc((size_t)NN * 4);
    int* col      = (int*)alloc((size_t)(EE + NN) * 4);
    float* pooled = (float*)alloc((size_t)BB * 128 * 4);
    unsigned short* g8b = (unsigned short*)alloc((size_t)BB * 128 * 2);
    unsigned short* Wt  = (unsigned short*)alloc((size_t)32768 * 2);
    unsigned short* W1t = (unsigned short*)alloc((size_t)98304 * 2);
    unsigned short* W2t = (unsigned short*)alloc((size_t)32768 * 2);
    int* bsum = (int*)alloc((size_t)NBLK * 4);
    int* boff = (int*)alloc((size_t)NBLK * 4);

    hipLaunchKernelGGL(k_init, dim3((NN + 255) / 256), dim3(256), 0, stream, cur, pooled);
    hipLaunchKernelGGL(k_count, dim3((EE + 255) / 256), dim3(256), 0, stream, ei, cur);
    hipLaunchKernelGGL(k_scanA, dim3(NBLK), dim3(256), 0, stream, cur, row_ptr, bsum);
    hipLaunchKernelGGL(k_scanB, dim3(1), dim3(256), 0, stream, bsum, boff);
    hipLaunchKernelGGL(k_scanC, dim3(NBLK), dim3(256), 0, stream, row_ptr, boff);
    hipLaunchKernelGGL(k_scatter, dim3((EE + NN + 255) / 256), dim3(256), 0, stream, ei, row_ptr, cur, col);
    hipLaunchKernelGGL(k_convw, dim3(640), dim3(256), 0, stream,
                       locW, regW, fu_W1, fu_W2, Wt, W1t, W2t);
    hipLaunchKernelGGL(k_gemm1, dim3((NN + 63) / 64), dim3(256), 0, stream,
                       x, Wt, loc_as, loc_ad, reg_as, reg_ad,
                       hc, als_l, ald_l, als_r, ald_r);
    hipLaunchKernelGGL(k_pool, dim3((NN + 255) / 256), dim3(256), 0, stream, x, batch, pooled);
    hipLaunchKernelGGL(k_gfeat8, dim3(BB), dim3(256), 0, stream,
                       pooled, batch, gp_W1, gp_b1, gp_W2, gp_b2, g8b);
    hipLaunchKernelGGL(k_gat, dim3(NN / 4), dim3(256), 0, stream,
                       row_ptr, col, hc, als_l, ald_l, als_r, ald_r, x,
                       loc_bi, loc_g, loc_b, reg_bi, reg_g, reg_b,
                       localb, regionalb);
    hipLaunchKernelGGL(k_fusedm, dim3((NN + 63) / 64), dim3(256), 0, stream,
                       localb, regionalb, g8b, batch,
                       W1t, fu_b1, W2t, fu_b2, fu_lg, fu_lb, out);
}

// Round 8
// 311.556 us; speedup vs baseline: 1.0170x; 1.0005x over previous
//
#include <hip/hip_runtime.h>

#define NN 50000
#define EE 800000
#define FF 128
#define HH 4
#define BB 8
#define NEG 0.2f
#define NBLK ((NN + 255) / 256)   // 196

typedef __attribute__((ext_vector_type(8))) short s8v;
typedef __attribute__((ext_vector_type(4))) float f4v;

__device__ __forceinline__ unsigned short f2b(float f) {
    union { float f; unsigned u; } v; v.f = f;
    unsigned r = v.u + 0x7fffu + ((v.u >> 16) & 1u);
    return (unsigned short)(r >> 16);
}
__device__ __forceinline__ float b2f(unsigned short h) {
    union { unsigned u; float f; } v; v.u = ((unsigned)h) << 16;
    return v.f;
}
__device__ __forceinline__ float uasf(unsigned u) {
    union { unsigned u; float f; } v; v.u = u; return v.f;
}
__device__ __forceinline__ float lrelu(float t) { return t > 0.f ? t : NEG * t; }

// ---------------- prep: weight transpose/convert + cur=1 + pooled=0 ----------------
__global__ void k_prep(const float* __restrict__ locW, const float* __restrict__ regW,
                       const float* __restrict__ W1, const float* __restrict__ W2,
                       unsigned short* __restrict__ Wt, unsigned short* __restrict__ W1t,
                       unsigned short* __restrict__ W2t, int* cur, float* pooled) {
    int i = blockIdx.x * 256 + threadIdx.x;
    if (i < 32768) {
        int n = i >> 7, k = i & 127;
        float v = n < 128 ? locW[k * 128 + n] : regW[k * 128 + n - 128];
        Wt[i] = f2b(v);
    } else if (i < 131072) {
        int j = i - 32768; int n = j / 384, k = j - n * 384;
        W1t[j] = f2b(W1[k * 256 + n]);
    } else if (i < 163840) {
        int j = i - 131072; int n = j >> 8, k = j & 255;
        W2t[j] = f2b(W2[k * 128 + n]);
    } else {
        int j = i - 163840;
        if (j < NN) cur[j] = 1;
        if (j < BB * FF) pooled[j] = 0.f;
    }
}

// ---------------- count in-degree ----------------
__global__ void k_count(const int* __restrict__ ei, int* cur) {
    int i = blockIdx.x * 256 + threadIdx.x;
    if (i < EE) atomicAdd(&cur[ei[EE + i]], 1);
}

// ---------------- 3-phase parallel scan ----------------
__global__ __launch_bounds__(256) void k_scanA(int* cur, int* row_ptr, int* bsum) {
    __shared__ int wsum[4];
    int b = blockIdx.x, t = threadIdx.x;
    int i = b * 256 + t;
    int v = (i < NN) ? cur[i] : 0;
    if (i < NN) cur[i] = 0;
    int lane = t & 63, w = t >> 6;
    int sc = v;
#pragma unroll
    for (int off = 1; off < 64; off <<= 1) {
        int n = __shfl_up(sc, off);
        if (lane >= off) sc += n;
    }
    if (lane == 63) wsum[w] = sc;
    __syncthreads();
    int woff = 0;
    for (int k = 0; k < w; k++) woff += wsum[k];
    int incl = sc + woff;
    if (i < NN) row_ptr[i + 1] = incl;
    if (t == 255) bsum[b] = incl;
    if (i == 0) row_ptr[0] = 0;
}

__global__ __launch_bounds__(256) void k_scanB(const int* __restrict__ bsum, int* boff) {
    __shared__ int wsum[4];
    int t = threadIdx.x;
    int v = (t < NBLK) ? bsum[t] : 0;
    int lane = t & 63, w = t >> 6;
    int sc = v;
#pragma unroll
    for (int off = 1; off < 64; off <<= 1) {
        int n = __shfl_up(sc, off);
        if (lane >= off) sc += n;
    }
    if (lane == 63) wsum[w] = sc;
    __syncthreads();
    int woff = 0;
    for (int k = 0; k < w; k++) woff += wsum[k];
    if (t < NBLK) boff[t] = sc + woff - v;
}

__global__ __launch_bounds__(256) void k_scanC(int* row_ptr, const int* __restrict__ boff) {
    int i = blockIdx.x * 256 + threadIdx.x;
    if (i < NN) row_ptr[i + 1] += boff[blockIdx.x];
}

// ---------------- scatter edges (and self loops) into CSR ----------------
__global__ void k_scatter(const int* __restrict__ ei, const int* __restrict__ row_ptr,
                          int* cur, int* col) {
    int i = blockIdx.x * 256 + threadIdx.x;
    if (i < EE) {
        int s = ei[i], d = ei[EE + i];
        int p = atomicAdd(&cur[d], 1);
        col[row_ptr[d] + p] = s;
    } else if (i < EE + NN) {
        int n = i - EE;
        int p = atomicAdd(&cur[n], 1);
        col[row_ptr[n] + p] = n;
    }
}

// ---------------- GEMM1 (MFMA): h = bf16(x) @ W -> interleaved hc; alpha epilogue ----------------
__global__ __launch_bounds__(256) void k_gemm1(
    const float* __restrict__ x,
    const unsigned short* __restrict__ Wt,
    const float* __restrict__ loc_as, const float* __restrict__ loc_ad,
    const float* __restrict__ reg_as, const float* __restrict__ reg_ad,
    unsigned* __restrict__ hc,
    float* __restrict__ als_l, float* __restrict__ ald_l,
    float* __restrict__ als_r, float* __restrict__ ald_r) {
    __shared__ unsigned short As[4 * 64 * 8];
    __shared__ unsigned short Bs[4 * 256 * 8];
    __shared__ unsigned short Hs[32 * 64 * 8];
    int t = threadIdx.x;
    int w = t >> 6, l = t & 63;
    int lq = l >> 4, lr = l & 15;
    int r0 = blockIdx.x * 64;

    int srow = t >> 2, sg = t & 3;
    int snode = r0 + srow; if (snode >= NN) snode = NN - 1;
    const float* xrow = x + (size_t)snode * 128 + sg * 8;

    f4v acc[4][4];
#pragma unroll
    for (int a0 = 0; a0 < 4; a0++)
#pragma unroll
        for (int b0 = 0; b0 < 4; b0++) acc[a0][b0] = (f4v){0.f, 0.f, 0.f, 0.f};

    for (int ks = 0; ks < 4; ++ks) {
        {
            float4 f0 = *(const float4*)(xrow + ks * 32);
            float4 f1 = *(const float4*)(xrow + ks * 32 + 4);
            unsigned short u[8] = { f2b(f0.x), f2b(f0.y), f2b(f0.z), f2b(f0.w),
                                    f2b(f1.x), f2b(f1.y), f2b(f1.z), f2b(f1.w) };
            *(s8v*)&As[(sg * 64 + srow) * 8] = *(const s8v*)u;
        }
#pragma unroll
        for (int it = 0; it < 4; ++it) {
            int c = t + it * 256;
            int g = c & 3, n = c >> 2;
            *(s8v*)&Bs[(g * 256 + n) * 8] = *(const s8v*)&Wt[(size_t)n * 128 + ks * 32 + g * 8];
        }
        __syncthreads();
        s8v af[4], bf[4];
#pragma unroll
        for (int rf = 0; rf < 4; ++rf) af[rf] = *(const s8v*)&As[(lq * 64 + rf * 16 + lr) * 8];
#pragma unroll
        for (int cf = 0; cf < 4; ++cf) bf[cf] = *(const s8v*)&Bs[(lq * 256 + w * 64 + cf * 16 + lr) * 8];
#pragma unroll
        for (int rf = 0; rf < 4; ++rf)
#pragma unroll
            for (int cf = 0; cf < 4; ++cf)
                acc[rf][cf] = __builtin_amdgcn_mfma_f32_16x16x32_bf16(af[rf], bf[cf], acc[rf][cf], 0, 0, 0);
        __syncthreads();
    }
#pragma unroll
    for (int cf = 0; cf < 4; ++cf) {
        int c = w * 64 + cf * 16 + lr;
#pragma unroll
        for (int rf = 0; rf < 4; ++rf)
#pragma unroll
            for (int i = 0; i < 4; ++i) {
                int row = rf * 16 + lq * 4 + i;
                Hs[((c >> 3) * 64 + row) * 8 + (c & 7)] = f2b(acc[rf][cf][i]);
            }
    }
    __syncthreads();
    // flush interleaved: hc[node*128 + fp*2] = {loc pair}, +1 = {reg pair}
#pragma unroll
    for (int it = 0; it < 16; ++it) {
        int idx = t + it * 256;
        int row = idx >> 6, fp = idx & 63;
        int node = r0 + row;
        if (node < NN) {
            int c0 = 2 * fp;
            int c1 = 128 + 2 * fp;
            unsigned lo = *(const unsigned*)&Hs[((c0 >> 3) * 64 + row) * 8 + (c0 & 7)];
            unsigned hi = *(const unsigned*)&Hs[((c1 >> 3) * 64 + row) * 8 + (c1 & 7)];
            uint2 p; p.x = lo; p.y = hi;
            *(uint2*)&hc[(size_t)node * 128 + fp * 2] = p;
        }
    }
#pragma unroll
    for (int it = 0; it < 4; ++it) {
        int row = it * 16 + (t >> 4);
        int node = r0 + row;
        int q = t & 15;
        int gat = q >> 3, sd = (q >> 2) & 1, head = q & 3;
        const float* av = gat ? (sd ? reg_ad : reg_as) : (sd ? loc_ad : loc_as);
        float s = 0.f;
        int cbase = gat * 128 + head * 32;
        for (int d = 0; d < 32; ++d) {
            int c = cbase + d;
            s += b2f(Hs[((c >> 3) * 64 + row) * 8 + (c & 7)]) * av[head * 32 + d];
        }
        if (node < NN) {
            float* outp = gat ? (sd ? ald_r : als_r) : (sd ? ald_l : als_l);
            outp[(size_t)node * 4 + head] = s;
        }
    }
}

// ---------------- pooling ----------------
__global__ void k_pool(const float* __restrict__ x, const int* __restrict__ batch,
                       float* pooled) {
    int t = threadIdx.x;
    int f = t & 127, half = t >> 7;
    int rstart = blockIdx.x * 256;
    int rend = rstart + 256; if (rend > NN) rend = NN;
    float acc = 0.f; int cur_b = -1;
    for (int r = rstart + half; r < rend; r += 2) {
        int b = batch[r];
        if (b != cur_b) {
            if (cur_b >= 0) atomicAdd(&pooled[cur_b * 128 + f], acc);
            cur_b = b; acc = 0.f;
        }
        acc += x[r * 128 + f];
    }
    if (cur_b >= 0) atomicAdd(&pooled[cur_b * 128 + f], acc);
}

// ---------------- gfeat: one block per graph ----------------
__global__ __launch_bounds__(256) void k_gfeat8(
    const float* __restrict__ pooled, const int* __restrict__ batch,
    const float* __restrict__ W1, const float* __restrict__ b1,
    const float* __restrict__ W2, const float* __restrict__ b2,
    unsigned short* __restrict__ g8b) {
    __shared__ float mean_s[128];
    __shared__ float hid_s[128];
    __shared__ float part[256];
    __shared__ int bnd[2];
    int b = blockIdx.x, t = threadIdx.x;
    if (t < 2) {
        int target = b + t;
        int lo = 0, hi = NN;
        while (lo < hi) { int mid = (lo + hi) >> 1; if (batch[mid] < target) lo = mid + 1; else hi = mid; }
        bnd[t] = lo;
    }
    __syncthreads();
    int cnt = bnd[1] - bnd[0];
    float inv = cnt ? 1.f / (float)cnt : 0.f;
    if (t < 128) mean_s[t] = pooled[b * 128 + t] * inv;
    __syncthreads();
    int c = t & 127, kh = t >> 7;
    float a = 0.f;
    for (int k = kh * 64; k < kh * 64 + 64; k++) a += mean_s[k] * W1[k * 128 + c];
    part[t] = a;
    __syncthreads();
    if (t < 128) hid_s[t] = fmaxf(part[t] + part[t + 128] + b1[t], 0.f);
    __syncthreads();
    float a2 = 0.f;
    for (int k = kh * 64; k < kh * 64 + 64; k++) a2 += hid_s[k] * W2[k * 128 + c];
    part[t] = a2;
    __syncthreads();
    if (t < 128) g8b[b * 128 + t] = f2b(part[t] + part[t + 128] + b2[t]);
}

// ---------------- GAT aggregate v6: 2 edges/iter (even/odd half-waves), dwordx4 gather ----------------
__global__ __launch_bounds__(256) void k_gat(
    const int* __restrict__ row_ptr, const int* __restrict__ col,
    const unsigned* __restrict__ hc,
    const float* __restrict__ als_l, const float* __restrict__ ald_l,
    const float* __restrict__ als_r, const float* __restrict__ ald_r,
    const float* __restrict__ x,
    const float* __restrict__ loc_bias, const float* __restrict__ loc_g, const float* __restrict__ loc_b,
    const float* __restrict__ reg_bias, const float* __restrict__ reg_g, const float* __restrict__ reg_b,
    unsigned short* __restrict__ out_local, unsigned short* __restrict__ out_reg) {
    __shared__ float exA[4][64][4];
    __shared__ float exB[4][64][4];
    __shared__ int   colb[4][64];
    __shared__ int   degs[4];
    int w = threadIdx.x >> 6, lane = threadIdx.x & 63;
    int half = lane >> 5, j = lane & 31;   // j: feature-quad index, features 4j..4j+3
    int h2 = j >> 3;                        // head of features 4j..4j+3
    int node = blockIdx.x * 4 + w;
    int rp0 = row_ptr[node];
    int deg = row_ptr[node + 1] - rp0;
    if (lane == 0) degs[w] = deg;
    float4 adL = *(const float4*)&ald_l[(size_t)node * 4];
    float4 adR = *(const float4*)&ald_r[(size_t)node * 4];
    __syncthreads();
    int maxdeg = max(max(degs[0], degs[1]), max(degs[2], degs[3]));
    int chunks = (maxdeg + 63) >> 6;

    // sweep 1: lane-parallel exp + sums; LDS stage (zero-filled) valid for serial iff chunks==1
    float sL0 = 0.f, sL1 = 0.f, sL2 = 0.f, sL3 = 0.f;
    float sR0 = 0.f, sR1 = 0.f, sR2 = 0.f, sR3 = 0.f;
    for (int base = 0; base < deg; base += 64) {
        int i = base + lane;
        bool v = i < deg;
        int s = col[rp0 + (v ? i : deg - 1)];
        float4 aL = *(const float4*)&als_l[(size_t)s * 4];
        float4 aR = *(const float4*)&als_r[(size_t)s * 4];
        float e0 = __expf(lrelu(aL.x + adL.x));
        float e1 = __expf(lrelu(aL.y + adL.y));
        float e2 = __expf(lrelu(aL.z + adL.z));
        float e3 = __expf(lrelu(aL.w + adL.w));
        float f0 = __expf(lrelu(aR.x + adR.x));
        float f1 = __expf(lrelu(aR.y + adR.y));
        float f2 = __expf(lrelu(aR.z + adR.z));
        float f3 = __expf(lrelu(aR.w + adR.w));
        if (!v) { e0 = e1 = e2 = e3 = f0 = f1 = f2 = f3 = 0.f; }
        *(float4*)&exA[w][lane][0] = make_float4(e0, e1, e2, e3);
        *(float4*)&exB[w][lane][0] = make_float4(f0, f1, f2, f3);
        colb[w][lane] = s;
        sL0 += e0; sL1 += e1; sL2 += e2; sL3 += e3;
        sR0 += f0; sR1 += f1; sR2 += f2; sR3 += f3;
    }
    __syncthreads();
#pragma unroll
    for (int off = 32; off; off >>= 1) {
        sL0 += __shfl_xor(sL0, off); sL1 += __shfl_xor(sL1, off);
        sL2 += __shfl_xor(sL2, off); sL3 += __shfl_xor(sL3, off);
        sR0 += __shfl_xor(sR0, off); sR1 += __shfl_xor(sR1, off);
        sR2 += __shfl_xor(sR2, off); sR3 += __shfl_xor(sR3, off);
    }
    float iA = (h2 & 2) ? ((h2 & 1) ? 1.f / sL3 : 1.f / sL2)
                        : ((h2 & 1) ? 1.f / sL1 : 1.f / sL0);
    float iB = (h2 & 2) ? ((h2 & 1) ? 1.f / sR3 : 1.f / sR2)
                        : ((h2 & 1) ? 1.f / sR1 : 1.f / sR0);

    float aL0 = 0.f, aL1 = 0.f, aL2 = 0.f, aL3 = 0.f;
    float bR0 = 0.f, bR1 = 0.f, bR2 = 0.f, bR3 = 0.f;
    const uint4* hc4 = (const uint4*)hc;   // 16B units: node*32 + j
    if (chunks == 1) {
        int npair = (deg + 1) >> 1;
#pragma unroll 4
        for (int it = 0; it < npair; ++it) {
            int e = 2 * it + half;         // ex/col zero-padded beyond deg
            int s = colb[w][e];
            float eA = exA[w][e][h2];
            float eB = exB[w][e][h2];
            uint4 u = hc4[(size_t)s * 32 + j];
            aL0 += eA * uasf(u.x << 16);
            aL1 += eA * uasf(u.x & 0xffff0000u);
            bR0 += eB * uasf(u.y << 16);
            bR1 += eB * uasf(u.y & 0xffff0000u);
            aL2 += eA * uasf(u.z << 16);
            aL3 += eA * uasf(u.z & 0xffff0000u);
            bR2 += eB * uasf(u.w << 16);
            bR3 += eB * uasf(u.w & 0xffff0000u);
        }
    } else {
        for (int c = 0; c < chunks; ++c) {
            int base = c * 64, i = base + lane;
            bool v = i < deg;
            int s0 = col[rp0 + (v ? i : deg - 1)];
            float4 aL = *(const float4*)&als_l[(size_t)s0 * 4];
            float4 aR = *(const float4*)&als_r[(size_t)s0 * 4];
            float e0 = __expf(lrelu(aL.x + adL.x));
            float e1 = __expf(lrelu(aL.y + adL.y));
            float e2 = __expf(lrelu(aL.z + adL.z));
            float e3 = __expf(lrelu(aL.w + adL.w));
            float f0 = __expf(lrelu(aR.x + adR.x));
            float f1 = __expf(lrelu(aR.y + adR.y));
            float f2 = __expf(lrelu(aR.z + adR.z));
            float f3 = __expf(lrelu(aR.w + adR.w));
            if (!v) { e0 = e1 = e2 = e3 = f0 = f1 = f2 = f3 = 0.f; }
            __syncthreads();   // protect prior chunk's readers
            *(float4*)&exA[w][lane][0] = make_float4(e0, e1, e2, e3);
            *(float4*)&exB[w][lane][0] = make_float4(f0, f1, f2, f3);
            colb[w][lane] = s0;
            __syncthreads();
            int nc = deg - base; nc = nc < 0 ? 0 : (nc > 64 ? 64 : nc);
            int npair = (nc + 1) >> 1;
#pragma unroll 4
            for (int it = 0; it < npair; ++it) {
                int e = 2 * it + half;
                int s = colb[w][e];
                float eA = exA[w][e][h2];
                float eB = exB[w][e][h2];
                uint4 u = hc4[(size_t)s * 32 + j];
                aL0 += eA * uasf(u.x << 16);
                aL1 += eA * uasf(u.x & 0xffff0000u);
                bR0 += eB * uasf(u.y << 16);
                bR1 += eB * uasf(u.y & 0xffff0000u);
                aL2 += eA * uasf(u.z << 16);
                aL3 += eA * uasf(u.z & 0xffff0000u);
                bR2 += eB * uasf(u.w << 16);
                bR3 += eB * uasf(u.w & 0xffff0000u);
            }
        }
    }

    // combine even/odd halves
    aL0 += __shfl_xor(aL0, 32); aL1 += __shfl_xor(aL1, 32);
    aL2 += __shfl_xor(aL2, 32); aL3 += __shfl_xor(aL3, 32);
    bR0 += __shfl_xor(bR0, 32); bR1 += __shfl_xor(bR1, 32);
    bR2 += __shfl_xor(bR2, 32); bR3 += __shfl_xor(bR3, 32);

    // epilogue: bias + residual + LN over features 4j..4j+3 (32-lane groups, both halves identical)
    int f0i = 4 * j;
    float4 xr  = *(const float4*)&x[(size_t)node * 128 + f0i];
    float4 lbi = *(const float4*)&loc_bias[f0i];
    float4 rbi = *(const float4*)&reg_bias[f0i];
    float v0 = aL0 * iA + lbi.x + xr.x;
    float v1 = aL1 * iA + lbi.y + xr.y;
    float v2 = aL2 * iA + lbi.z + xr.z;
    float v3 = aL3 * iA + lbi.w + xr.w;
    float u0 = bR0 * iB + rbi.x + xr.x;
    float u1 = bR1 * iB + rbi.y + xr.y;
    float u2 = bR2 * iB + rbi.z + xr.z;
    float u3 = bR3 * iB + rbi.w + xr.w;

    float sv = v0 + v1 + v2 + v3, su = u0 + u1 + u2 + u3;
#pragma unroll
    for (int off = 16; off; off >>= 1) { sv += __shfl_xor(sv, off); su += __shfl_xor(su, off); }
    float mv = sv * (1.f / 128.f), mu = su * (1.f / 128.f);
    float dv0 = v0 - mv, dv1 = v1 - mv, dv2 = v2 - mv, dv3 = v3 - mv;
    float du0 = u0 - mu, du1 = u1 - mu, du2 = u2 - mu, du3 = u3 - mu;
    float qv = dv0 * dv0 + dv1 * dv1 + dv2 * dv2 + dv3 * dv3;
    float qu = du0 * du0 + du1 * du1 + du2 * du2 + du3 * du3;
#pragma unroll
    for (int off = 16; off; off >>= 1) { qv += __shfl_xor(qv, off); qu += __shfl_xor(qu, off); }
    float rv = rsqrtf(qv * (1.f / 128.f) + 1e-5f), ru = rsqrtf(qu * (1.f / 128.f) + 1e-5f);
    if (half == 0) {
        float4 lg = *(const float4*)&loc_g[f0i], lb2 = *(const float4*)&loc_b[f0i];
        float4 rg = *(const float4*)&reg_g[f0i], rb2 = *(const float4*)&reg_b[f0i];
        uint2 pv, pu;
        pv.x = (unsigned)f2b(dv0 * rv * lg.x + lb2.x) | ((unsigned)f2b(dv1 * rv * lg.y + lb2.y) << 16);
        pv.y = (unsigned)f2b(dv2 * rv * lg.z + lb2.z) | ((unsigned)f2b(dv3 * rv * lg.w + lb2.w) << 16);
        pu.x = (unsigned)f2b(du0 * ru * rg.x + rb2.x) | ((unsigned)f2b(du1 * ru * rg.y + rb2.y) << 16);
        pu.y = (unsigned)f2b(du2 * ru * rg.z + rb2.z) | ((unsigned)f2b(du3 * ru * rg.w + rb2.w) << 16);
        *(uint2*)&out_local[(size_t)node * 128 + f0i] = pv;
        *(uint2*)&out_reg[(size_t)node * 128 + f0i]   = pu;
    }
}

// ---------------- fused MLP (MFMA) ----------------
__global__ __launch_bounds__(256) void k_fusedm(
    const unsigned short* __restrict__ localb, const unsigned short* __restrict__ regionalb,
    const unsigned short* __restrict__ g8b, const int* __restrict__ batch,
    const unsigned short* __restrict__ W1t, const float* __restrict__ b1,
    const unsigned short* __restrict__ W2t, const float* __restrict__ b2,
    const float* __restrict__ lng, const float* __restrict__ lnb,
    float* __restrict__ out) {
    __shared__ unsigned short As[4 * 64 * 8];
    __shared__ unsigned short Bs[4 * 256 * 8];
    __shared__ unsigned short Hs[32 * 64 * 8];
    __shared__ unsigned short W2s[4 * 128 * 8];
    int t = threadIdx.x;
    int w = t >> 6, l = t & 63;
    int lq = l >> 4, lr = l & 15;
    int r0 = blockIdx.x * 64;

    int srow = t >> 2, sg = t & 3;
    int snode = r0 + srow; if (snode >= NN) snode = NN - 1;
    int sbatch = batch[snode];

    f4v acc[4][4];
#pragma unroll
    for (int a0 = 0; a0 < 4; a0++)
#pragma unroll
        for (int b0 = 0; b0 < 4; b0++) acc[a0][b0] = (f4v){0.f, 0.f, 0.f, 0.f};

    for (int ks = 0; ks < 12; ++ks) {
        int seg = ks >> 2;
        int ko = (ks & 3) * 32 + sg * 8;
        const unsigned short* src =
            seg == 0 ? localb + (size_t)snode * 128 + ko :
            seg == 1 ? regionalb + (size_t)snode * 128 + ko :
                       g8b + (size_t)sbatch * 128 + ko;
        *(s8v*)&As[(sg * 64 + srow) * 8] = *(const s8v*)src;
#pragma unroll
        for (int it = 0; it < 4; ++it) {
            int c = t + it * 256;
            int g = c & 3, n = c >> 2;
            *(s8v*)&Bs[(g * 256 + n) * 8] = *(const s8v*)&W1t[(size_t)n * 384 + ks * 32 + g * 8];
        }
        __syncthreads();
        s8v af[4], bf[4];
#pragma unroll
        for (int rf = 0; rf < 4; ++rf) af[rf] = *(const s8v*)&As[(lq * 64 + rf * 16 + lr) * 8];
#pragma unroll
        for (int cf = 0; cf < 4; ++cf) bf[cf] = *(const s8v*)&Bs[(lq * 256 + w * 64 + cf * 16 + lr) * 8];
#pragma unroll
        for (int rf = 0; rf < 4; ++rf)
#pragma unroll
            for (int cf = 0; cf < 4; ++cf)
                acc[rf][cf] = __builtin_amdgcn_mfma_f32_16x16x32_bf16(af[rf], bf[cf], acc[rf][cf], 0, 0, 0);
        __syncthreads();
    }
#pragma unroll
    for (int cf = 0; cf < 4; ++cf) {
        int c = w * 64 + cf * 16 + lr;
        float bc = b1[c];
#pragma unroll
        for (int rf = 0; rf < 4; ++rf)
#pragma unroll
            for (int i = 0; i < 4; ++i) {
                int row = rf * 16 + lq * 4 + i;
                float v0 = acc[rf][cf][i] + bc;
                Hs[((c >> 3) * 64 + row) * 8 + (c & 7)] = f2b(v0 > 0.f ? v0 : 0.f);
            }
    }
    __syncthreads();
    f4v a2[8];
#pragma unroll
    for (int cf = 0; cf < 8; ++cf) a2[cf] = (f4v){0.f, 0.f, 0.f, 0.f};
    for (int ks = 0; ks < 8; ++ks) {
#pragma unroll
        for (int it = 0; it < 2; ++it) {
            int c = t + it * 256;
            int g = c & 3, n = c >> 2;
            *(s8v*)&W2s[(g * 128 + n) * 8] = *(const s8v*)&W2t[(size_t)n * 256 + ks * 32 + g * 8];
        }
        __syncthreads();
        s8v af = *(const s8v*)&Hs[((ks * 4 + lq) * 64 + w * 16 + lr) * 8];
#pragma unroll
        for (int cf = 0; cf < 8; ++cf) {
            s8v bfv = *(const s8v*)&W2s[(lq * 128 + cf * 16 + lr) * 8];
            a2[cf] = __builtin_amdgcn_mfma_f32_16x16x32_bf16(af, bfv, a2[cf], 0, 0, 0);
        }
        __syncthreads();
    }
    float b2c[8], gc[8], bc2[8];
#pragma unroll
    for (int cf = 0; cf < 8; ++cf) {
        int c = cf * 16 + lr;
        b2c[cf] = b2[c]; gc[cf] = lng[c]; bc2[cf] = lnb[c];
    }
#pragma unroll
    for (int i = 0; i < 4; ++i) {
        int row = w * 16 + lq * 4 + i;
        int node = r0 + row;
        float vals[8]; float s = 0.f;
#pragma unroll
        for (int cf = 0; cf < 8; ++cf) { vals[cf] = a2[cf][i] + b2c[cf]; s += vals[cf]; }
        s += __shfl_xor(s, 1); s += __shfl_xor(s, 2); s += __shfl_xor(s, 4); s += __shfl_xor(s, 8);
        float mean = s * (1.f / 128.f);
        float vs = 0.f;
#pragma unroll
        for (int cf = 0; cf < 8; ++cf) { float d = vals[cf] - mean; vs += d * d; }
        vs += __shfl_xor(vs, 1); vs += __shfl_xor(vs, 2); vs += __shfl_xor(vs, 4); vs += __shfl_xor(vs, 8);
        float rstd = rsqrtf(vs * (1.f / 128.f) + 1e-5f);
        if (node < NN) {
#pragma unroll
            for (int cf = 0; cf < 8; ++cf)
                out[(size_t)node * 128 + cf * 16 + lr] = (vals[cf] - mean) * rstd * gc[cf] + bc2[cf];
        }
    }
}

extern "C" void kernel_launch(void* const* d_in, const int* in_sizes, int n_in,
                              void* d_out, int out_size, void* d_ws, size_t ws_size,
                              hipStream_t stream) {
    const float* x      = (const float*)d_in[0];
    const int*   ei     = (const int*)d_in[1];
    const int*   batch  = (const int*)d_in[2];
    const float* locW   = (const float*)d_in[3];
    const float* loc_as = (const float*)d_in[4];
    const float* loc_ad = (const float*)d_in[5];
    const float* loc_bi = (const float*)d_in[6];
    const float* loc_g  = (const float*)d_in[7];
    const float* loc_b  = (const float*)d_in[8];
    const float* regW   = (const float*)d_in[9];
    const float* reg_as = (const float*)d_in[10];
    const float* reg_ad = (const float*)d_in[11];
    const float* reg_bi = (const float*)d_in[12];
    const float* reg_g  = (const float*)d_in[13];
    const float* reg_b  = (const float*)d_in[14];
    const float* gp_W1  = (const float*)d_in[15];
    const float* gp_b1  = (const float*)d_in[16];
    const float* gp_W2  = (const float*)d_in[17];
    const float* gp_b2  = (const float*)d_in[18];
    const float* fu_W1  = (const float*)d_in[19];
    const float* fu_b1  = (const float*)d_in[20];
    const float* fu_W2  = (const float*)d_in[21];
    const float* fu_b2  = (const float*)d_in[22];
    const float* fu_lg  = (const float*)d_in[23];
    const float* fu_lb  = (const float*)d_in[24];
    float* out = (float*)d_out;

    char* ws = (char*)d_ws;
    size_t off = 0;
    auto alloc = [&](size_t bytes) { void* p = ws + off; off += (bytes + 255) & ~(size_t)255; return p; };
    unsigned* hc              = (unsigned*)alloc((size_t)NN * 128 * 4);
    unsigned short* localb    = (unsigned short*)alloc((size_t)NN * 128 * 2);
    unsigned short* regionalb = (unsigned short*)alloc((size_t)NN * 128 * 2);
    float* als_l  = (float*)alloc((size_t)NN * 4 * 4);
    float* ald_l  = (float*)alloc((size_t)NN * 4 * 4);
    float* als_r  = (float*)alloc((size_t)NN * 4 * 4);
    float* ald_r  = (float*)alloc((size_t)NN * 4 * 4);
    int* row_ptr  = (int*)alloc((size_t)(NN + 1) * 4);
    int* cur      = (int*)alloc((size_t)NN * 4);
    int* col      = (int*)alloc((size_t)(EE + NN) * 4);
    float* pooled = (float*)alloc((size_t)BB * 128 * 4);
    unsigned short* g8b = (unsigned short*)alloc((size_t)BB * 128 * 2);
    unsigned short* Wt  = (unsigned short*)alloc((size_t)32768 * 2);
    unsigned short* W1t = (unsigned short*)alloc((size_t)98304 * 2);
    unsigned short* W2t = (unsigned short*)alloc((size_t)32768 * 2);
    int* bsum = (int*)alloc((size_t)NBLK * 4);
    int* boff = (int*)alloc((size_t)NBLK * 4);

    // prep covers: 640 blocks conv + 196 blocks init
    hipLaunchKernelGGL(k_prep, dim3(640 + NBLK), dim3(256), 0, stream,
                       locW, regW, fu_W1, fu_W2, Wt, W1t, W2t, cur, pooled);
    hipLaunchKernelGGL(k_count, dim3((EE + 255) / 256), dim3(256), 0, stream, ei, cur);
    hipLaunchKernelGGL(k_scanA, dim3(NBLK), dim3(256), 0, stream, cur, row_ptr, bsum);
    hipLaunchKernelGGL(k_scanB, dim3(1), dim3(256), 0, stream, bsum, boff);
    hipLaunchKernelGGL(k_scanC, dim3(NBLK), dim3(256), 0, stream, row_ptr, boff);
    hipLaunchKernelGGL(k_scatter, dim3((EE + NN + 255) / 256), dim3(256), 0, stream, ei, row_ptr, cur, col);
    hipLaunchKernelGGL(k_gemm1, dim3((NN + 63) / 64), dim3(256), 0, stream,
                       x, Wt, loc_as, loc_ad, reg_as, reg_ad,
                       hc, als_l, ald_l, als_r, ald_r);
    hipLaunchKernelGGL(k_pool, dim3((NN + 255) / 256), dim3(256), 0, stream, x, batch, pooled);
    hipLaunchKernelGGL(k_gfeat8, dim3(BB), dim3(256), 0, stream,
                       pooled, batch, gp_W1, gp_b1, gp_W2, gp_b2, g8b);
    hipLaunchKernelGGL(k_gat, dim3(NN / 4), dim3(256), 0, stream,
                       row_ptr, col, hc, als_l, ald_l, als_r, ald_r, x,
                       loc_bi, loc_g, loc_b, reg_bi, reg_g, reg_b,
                       localb, regionalb);
    hipLaunchKernelGGL(k_fusedm, dim3((NN + 63) / 64), dim3(256), 0, stream,
                       localb, regionalb, g8b, batch,
                       W1t, fu_b1, W2t, fu_b2, fu_lg, fu_lb, out);
}

// Round 9
// 311.306 us; speedup vs baseline: 1.0178x; 1.0008x over previous
//
#include <hip/hip_runtime.h>

#define NN 50000
#define EE 800000
#define FF 128
#define HH 4
#define BB 8
#define NEG 0.2f
#define NBLK ((NN + 255) / 256)   // 196

typedef __attribute__((ext_vector_type(8))) short s8v;
typedef __attribute__((ext_vector_type(4))) float f4v;

__device__ __forceinline__ unsigned short f2b(float f) {
    union { float f; unsigned u; } v; v.f = f;
    unsigned r = v.u + 0x7fffu + ((v.u >> 16) & 1u);
    return (unsigned short)(r >> 16);
}
__device__ __forceinline__ float b2f(unsigned short h) {
    union { unsigned u; float f; } v; v.u = ((unsigned)h) << 16;
    return v.f;
}
__device__ __forceinline__ float uasf(unsigned u) {
    union { unsigned u; float f; } v; v.u = u; return v.f;
}
__device__ __forceinline__ float lrelu(float t) { return t > 0.f ? t : NEG * t; }

// ---------------- prep: weight transpose/convert + cur=1 + pooled=0 ----------------
__global__ void k_prep(const float* __restrict__ locW, const float* __restrict__ regW,
                       const float* __restrict__ W1, const float* __restrict__ W2,
                       unsigned short* __restrict__ Wt, unsigned short* __restrict__ W1t,
                       unsigned short* __restrict__ W2t, int* cur, float* pooled) {
    int i = blockIdx.x * 256 + threadIdx.x;
    if (i < 32768) {
        int n = i >> 7, k = i & 127;
        float v = n < 128 ? locW[k * 128 + n] : regW[k * 128 + n - 128];
        Wt[i] = f2b(v);
    } else if (i < 131072) {
        int j = i - 32768; int n = j / 384, k = j - n * 384;
        W1t[j] = f2b(W1[k * 256 + n]);
    } else if (i < 163840) {
        int j = i - 131072; int n = j >> 8, k = j & 255;
        W2t[j] = f2b(W2[k * 128 + n]);
    } else {
        int j = i - 163840;
        if (j < NN) cur[j] = 1;
        if (j < BB * FF) pooled[j] = 0.f;
    }
}

// ---------------- count in-degree ----------------
__global__ void k_count(const int* __restrict__ ei, int* cur) {
    int i = blockIdx.x * 256 + threadIdx.x;
    if (i < EE) atomicAdd(&cur[ei[EE + i]], 1);
}

// ---------------- 3-phase parallel scan ----------------
__global__ __launch_bounds__(256) void k_scanA(int* cur, int* row_ptr, int* bsum) {
    __shared__ int wsum[4];
    int b = blockIdx.x, t = threadIdx.x;
    int i = b * 256 + t;
    int v = (i < NN) ? cur[i] : 0;
    if (i < NN) cur[i] = 0;
    int lane = t & 63, w = t >> 6;
    int sc = v;
#pragma unroll
    for (int off = 1; off < 64; off <<= 1) {
        int n = __shfl_up(sc, off);
        if (lane >= off) sc += n;
    }
    if (lane == 63) wsum[w] = sc;
    __syncthreads();
    int woff = 0;
    for (int k = 0; k < w; k++) woff += wsum[k];
    int incl = sc + woff;
    if (i < NN) row_ptr[i + 1] = incl;
    if (t == 255) bsum[b] = incl;
    if (i == 0) row_ptr[0] = 0;
}

__global__ __launch_bounds__(256) void k_scanB(const int* __restrict__ bsum, int* boff) {
    __shared__ int wsum[4];
    int t = threadIdx.x;
    int v = (t < NBLK) ? bsum[t] : 0;
    int lane = t & 63, w = t >> 6;
    int sc = v;
#pragma unroll
    for (int off = 1; off < 64; off <<= 1) {
        int n = __shfl_up(sc, off);
        if (lane >= off) sc += n;
    }
    if (lane == 63) wsum[w] = sc;
    __syncthreads();
    int woff = 0;
    for (int k = 0; k < w; k++) woff += wsum[k];
    if (t < NBLK) boff[t] = sc + woff - v;
}

__global__ __launch_bounds__(256) void k_scanC(int* row_ptr, const int* __restrict__ boff) {
    int i = blockIdx.x * 256 + threadIdx.x;
    if (i < NN) row_ptr[i + 1] += boff[blockIdx.x];
}

// ---------------- scatter edges (and self loops) into CSR ----------------
__global__ void k_scatter(const int* __restrict__ ei, const int* __restrict__ row_ptr,
                          int* cur, int* col) {
    int i = blockIdx.x * 256 + threadIdx.x;
    if (i < EE) {
        int s = ei[i], d = ei[EE + i];
        int p = atomicAdd(&cur[d], 1);
        col[row_ptr[d] + p] = s;
    } else if (i < EE + NN) {
        int n = i - EE;
        int p = atomicAdd(&cur[n], 1);
        col[row_ptr[n] + p] = n;
    }
}

// ---------------- GEMM1 (MFMA): h = bf16(x) @ W -> interleaved hc; alpha epilogue ----------------
__global__ __launch_bounds__(256) void k_gemm1(
    const float* __restrict__ x,
    const unsigned short* __restrict__ Wt,
    const float* __restrict__ loc_as, const float* __restrict__ loc_ad,
    const float* __restrict__ reg_as, const float* __restrict__ reg_ad,
    unsigned* __restrict__ hc,
    float* __restrict__ als_l, float* __restrict__ ald_l,
    float* __restrict__ als_r, float* __restrict__ ald_r) {
    __shared__ unsigned short As[4 * 64 * 8];
    __shared__ unsigned short Bs[4 * 256 * 8];
    __shared__ unsigned short Hs[32 * 64 * 8];
    int t = threadIdx.x;
    int w = t >> 6, l = t & 63;
    int lq = l >> 4, lr = l & 15;
    int r0 = blockIdx.x * 64;

    int srow = t >> 2, sg = t & 3;
    int snode = r0 + srow; if (snode >= NN) snode = NN - 1;
    const float* xrow = x + (size_t)snode * 128 + sg * 8;

    f4v acc[4][4];
#pragma unroll
    for (int a0 = 0; a0 < 4; a0++)
#pragma unroll
        for (int b0 = 0; b0 < 4; b0++) acc[a0][b0] = (f4v){0.f, 0.f, 0.f, 0.f};

    for (int ks = 0; ks < 4; ++ks) {
        {
            float4 f0 = *(const float4*)(xrow + ks * 32);
            float4 f1 = *(const float4*)(xrow + ks * 32 + 4);
            unsigned short u[8] = { f2b(f0.x), f2b(f0.y), f2b(f0.z), f2b(f0.w),
                                    f2b(f1.x), f2b(f1.y), f2b(f1.z), f2b(f1.w) };
            *(s8v*)&As[(sg * 64 + srow) * 8] = *(const s8v*)u;
        }
#pragma unroll
        for (int it = 0; it < 4; ++it) {
            int c = t + it * 256;
            int g = c & 3, n = c >> 2;
            *(s8v*)&Bs[(g * 256 + n) * 8] = *(const s8v*)&Wt[(size_t)n * 128 + ks * 32 + g * 8];
        }
        __syncthreads();
        s8v af[4], bf[4];
#pragma unroll
        for (int rf = 0; rf < 4; ++rf) af[rf] = *(const s8v*)&As[(lq * 64 + rf * 16 + lr) * 8];
#pragma unroll
        for (int cf = 0; cf < 4; ++cf) bf[cf] = *(const s8v*)&Bs[(lq * 256 + w * 64 + cf * 16 + lr) * 8];
#pragma unroll
        for (int rf = 0; rf < 4; ++rf)
#pragma unroll
            for (int cf = 0; cf < 4; ++cf)
                acc[rf][cf] = __builtin_amdgcn_mfma_f32_16x16x32_bf16(af[rf], bf[cf], acc[rf][cf], 0, 0, 0);
        __syncthreads();
    }
#pragma unroll
    for (int cf = 0; cf < 4; ++cf) {
        int c = w * 64 + cf * 16 + lr;
#pragma unroll
        for (int rf = 0; rf < 4; ++rf)
#pragma unroll
            for (int i = 0; i < 4; ++i) {
                int row = rf * 16 + lq * 4 + i;
                Hs[((c >> 3) * 64 + row) * 8 + (c & 7)] = f2b(acc[rf][cf][i]);
            }
    }
    __syncthreads();
    // flush interleaved: hc[node*128 + fp*2] = {loc pair}, +1 = {reg pair}
#pragma unroll
    for (int it = 0; it < 16; ++it) {
        int idx = t + it * 256;
        int row = idx >> 6, fp = idx & 63;
        int node = r0 + row;
        if (node < NN) {
            int c0 = 2 * fp;
            int c1 = 128 + 2 * fp;
            unsigned lo = *(const unsigned*)&Hs[((c0 >> 3) * 64 + row) * 8 + (c0 & 7)];
            unsigned hi = *(const unsigned*)&Hs[((c1 >> 3) * 64 + row) * 8 + (c1 & 7)];
            uint2 p; p.x = lo; p.y = hi;
            *(uint2*)&hc[(size_t)node * 128 + fp * 2] = p;
        }
    }
#pragma unroll
    for (int it = 0; it < 4; ++it) {
        int row = it * 16 + (t >> 4);
        int node = r0 + row;
        int q = t & 15;
        int gat = q >> 3, sd = (q >> 2) & 1, head = q & 3;
        const float* av = gat ? (sd ? reg_ad : reg_as) : (sd ? loc_ad : loc_as);
        float s = 0.f;
        int cbase = gat * 128 + head * 32;
        for (int d = 0; d < 32; ++d) {
            int c = cbase + d;
            s += b2f(Hs[((c >> 3) * 64 + row) * 8 + (c & 7)]) * av[head * 32 + d];
        }
        if (node < NN) {
            float* outp = gat ? (sd ? ald_r : als_r) : (sd ? ald_l : als_l);
            outp[(size_t)node * 4 + head] = s;
        }
    }
}

// ---------------- pooling ----------------
__global__ void k_pool(const float* __restrict__ x, const int* __restrict__ batch,
                       float* pooled) {
    int t = threadIdx.x;
    int f = t & 127, half = t >> 7;
    int rstart = blockIdx.x * 256;
    int rend = rstart + 256; if (rend > NN) rend = NN;
    float acc = 0.f; int cur_b = -1;
    for (int r = rstart + half; r < rend; r += 2) {
        int b = batch[r];
        if (b != cur_b) {
            if (cur_b >= 0) atomicAdd(&pooled[cur_b * 128 + f], acc);
            cur_b = b; acc = 0.f;
        }
        acc += x[r * 128 + f];
    }
    if (cur_b >= 0) atomicAdd(&pooled[cur_b * 128 + f], acc);
}

// ---------------- gfeat: one block per graph ----------------
__global__ __launch_bounds__(256) void k_gfeat8(
    const float* __restrict__ pooled, const int* __restrict__ batch,
    const float* __restrict__ W1, const float* __restrict__ b1,
    const float* __restrict__ W2, const float* __restrict__ b2,
    unsigned short* __restrict__ g8b) {
    __shared__ float mean_s[128];
    __shared__ float hid_s[128];
    __shared__ float part[256];
    __shared__ int bnd[2];
    int b = blockIdx.x, t = threadIdx.x;
    if (t < 2) {
        int target = b + t;
        int lo = 0, hi = NN;
        while (lo < hi) { int mid = (lo + hi) >> 1; if (batch[mid] < target) lo = mid + 1; else hi = mid; }
        bnd[t] = lo;
    }
    __syncthreads();
    int cnt = bnd[1] - bnd[0];
    float inv = cnt ? 1.f / (float)cnt : 0.f;
    if (t < 128) mean_s[t] = pooled[b * 128 + t] * inv;
    __syncthreads();
    int c = t & 127, kh = t >> 7;
    float a = 0.f;
    for (int k = kh * 64; k < kh * 64 + 64; k++) a += mean_s[k] * W1[k * 128 + c];
    part[t] = a;
    __syncthreads();
    if (t < 128) hid_s[t] = fmaxf(part[t] + part[t + 128] + b1[t], 0.f);
    __syncthreads();
    float a2 = 0.f;
    for (int k = kh * 64; k < kh * 64 + 64; k++) a2 += hid_s[k] * W2[k * 128 + c];
    part[t] = a2;
    __syncthreads();
    if (t < 128) g8b[b * 128 + t] = f2b(part[t] + part[t + 128] + b2[t]);
}

// ---------------- GAT aggregate v6: 2 edges/iter (even/odd half-waves), dwordx4 gather ----------------
__global__ __launch_bounds__(256) void k_gat(
    const int* __restrict__ row_ptr, const int* __restrict__ col,
    const unsigned* __restrict__ hc,
    const float* __restrict__ als_l, const float* __restrict__ ald_l,
    const float* __restrict__ als_r, const float* __restrict__ ald_r,
    const float* __restrict__ x,
    const float* __restrict__ loc_bias, const float* __restrict__ loc_g, const float* __restrict__ loc_b,
    const float* __restrict__ reg_bias, const float* __restrict__ reg_g, const float* __restrict__ reg_b,
    unsigned short* __restrict__ out_local, unsigned short* __restrict__ out_reg) {
    __shared__ float exA[4][64][4];
    __shared__ float exB[4][64][4];
    __shared__ int   colb[4][64];
    __shared__ int   degs[4];
    int w = threadIdx.x >> 6, lane = threadIdx.x & 63;
    int half = lane >> 5, j = lane & 31;   // j: feature-quad index, features 4j..4j+3
    int h2 = j >> 3;                        // head of features 4j..4j+3
    int node = blockIdx.x * 4 + w;
    int rp0 = row_ptr[node];
    int deg = row_ptr[node + 1] - rp0;
    if (lane == 0) degs[w] = deg;
    float4 adL = *(const float4*)&ald_l[(size_t)node * 4];
    float4 adR = *(const float4*)&ald_r[(size_t)node * 4];
    __syncthreads();
    int maxdeg = max(max(degs[0], degs[1]), max(degs[2], degs[3]));
    int chunks = (maxdeg + 63) >> 6;

    // sweep 1: lane-parallel exp + sums; LDS stage (zero-filled) valid for serial iff chunks==1
    float sL0 = 0.f, sL1 = 0.f, sL2 = 0.f, sL3 = 0.f;
    float sR0 = 0.f, sR1 = 0.f, sR2 = 0.f, sR3 = 0.f;
    for (int base = 0; base < deg; base += 64) {
        int i = base + lane;
        bool v = i < deg;
        int s = col[rp0 + (v ? i : deg - 1)];
        float4 aL = *(const float4*)&als_l[(size_t)s * 4];
        float4 aR = *(const float4*)&als_r[(size_t)s * 4];
        float e0 = __expf(lrelu(aL.x + adL.x));
        float e1 = __expf(lrelu(aL.y + adL.y));
        float e2 = __expf(lrelu(aL.z + adL.z));
        float e3 = __expf(lrelu(aL.w + adL.w));
        float f0 = __expf(lrelu(aR.x + adR.x));
        float f1 = __expf(lrelu(aR.y + adR.y));
        float f2 = __expf(lrelu(aR.z + adR.z));
        float f3 = __expf(lrelu(aR.w + adR.w));
        if (!v) { e0 = e1 = e2 = e3 = f0 = f1 = f2 = f3 = 0.f; }
        *(float4*)&exA[w][lane][0] = make_float4(e0, e1, e2, e3);
        *(float4*)&exB[w][lane][0] = make_float4(f0, f1, f2, f3);
        colb[w][lane] = s;
        sL0 += e0; sL1 += e1; sL2 += e2; sL3 += e3;
        sR0 += f0; sR1 += f1; sR2 += f2; sR3 += f3;
    }
    __syncthreads();
#pragma unroll
    for (int off = 32; off; off >>= 1) {
        sL0 += __shfl_xor(sL0, off); sL1 += __shfl_xor(sL1, off);
        sL2 += __shfl_xor(sL2, off); sL3 += __shfl_xor(sL3, off);
        sR0 += __shfl_xor(sR0, off); sR1 += __shfl_xor(sR1, off);
        sR2 += __shfl_xor(sR2, off); sR3 += __shfl_xor(sR3, off);
    }
    float iA = (h2 & 2) ? ((h2 & 1) ? 1.f / sL3 : 1.f / sL2)
                        : ((h2 & 1) ? 1.f / sL1 : 1.f / sL0);
    float iB = (h2 & 2) ? ((h2 & 1) ? 1.f / sR3 : 1.f / sR2)
                        : ((h2 & 1) ? 1.f / sR1 : 1.f / sR0);

    float aL0 = 0.f, aL1 = 0.f, aL2 = 0.f, aL3 = 0.f;
    float bR0 = 0.f, bR1 = 0.f, bR2 = 0.f, bR3 = 0.f;
    const uint4* hc4 = (const uint4*)hc;   // 16B units: node*32 + j
    if (chunks == 1) {
        int npair = (deg + 1) >> 1;
#pragma unroll 4
        for (int it = 0; it < npair; ++it) {
            int e = 2 * it + half;         // ex/col zero-padded beyond deg
            int s = colb[w][e];
            float eA = exA[w][e][h2];
            float eB = exB[w][e][h2];
            uint4 u = hc4[(size_t)s * 32 + j];
            aL0 += eA * uasf(u.x << 16);
            aL1 += eA * uasf(u.x & 0xffff0000u);
            bR0 += eB * uasf(u.y << 16);
            bR1 += eB * uasf(u.y & 0xffff0000u);
            aL2 += eA * uasf(u.z << 16);
            aL3 += eA * uasf(u.z & 0xffff0000u);
            bR2 += eB * uasf(u.w << 16);
            bR3 += eB * uasf(u.w & 0xffff0000u);
        }
    } else {
        for (int c = 0; c < chunks; ++c) {
            int base = c * 64, i = base + lane;
            bool v = i < deg;
            int s0 = col[rp0 + (v ? i : deg - 1)];
            float4 aL = *(const float4*)&als_l[(size_t)s0 * 4];
            float4 aR = *(const float4*)&als_r[(size_t)s0 * 4];
            float e0 = __expf(lrelu(aL.x + adL.x));
            float e1 = __expf(lrelu(aL.y + adL.y));
            float e2 = __expf(lrelu(aL.z + adL.z));
            float e3 = __expf(lrelu(aL.w + adL.w));
            float f0 = __expf(lrelu(aR.x + adR.x));
            float f1 = __expf(lrelu(aR.y + adR.y));
            float f2 = __expf(lrelu(aR.z + adR.z));
            float f3 = __expf(lrelu(aR.w + adR.w));
            if (!v) { e0 = e1 = e2 = e3 = f0 = f1 = f2 = f3 = 0.f; }
            __syncthreads();   // protect prior chunk's readers
            *(float4*)&exA[w][lane][0] = make_float4(e0, e1, e2, e3);
            *(float4*)&exB[w][lane][0] = make_float4(f0, f1, f2, f3);
            colb[w][lane] = s0;
            __syncthreads();
            int nc = deg - base; nc = nc < 0 ? 0 : (nc > 64 ? 64 : nc);
            int npair = (nc + 1) >> 1;
#pragma unroll 4
            for (int it = 0; it < npair; ++it) {
                int e = 2 * it + half;
                int s = colb[w][e];
                float eA = exA[w][e][h2];
                float eB = exB[w][e][h2];
                uint4 u = hc4[(size_t)s * 32 + j];
                aL0 += eA * uasf(u.x << 16);
                aL1 += eA * uasf(u.x & 0xffff0000u);
                bR0 += eB * uasf(u.y << 16);
                bR1 += eB * uasf(u.y & 0xffff0000u);
                aL2 += eA * uasf(u.z << 16);
                aL3 += eA * uasf(u.z & 0xffff0000u);
                bR2 += eB * uasf(u.w << 16);
                bR3 += eB * uasf(u.w & 0xffff0000u);
            }
        }
    }

    // combine even/odd halves
    aL0 += __shfl_xor(aL0, 32); aL1 += __shfl_xor(aL1, 32);
    aL2 += __shfl_xor(aL2, 32); aL3 += __shfl_xor(aL3, 32);
    bR0 += __shfl_xor(bR0, 32); bR1 += __shfl_xor(bR1, 32);
    bR2 += __shfl_xor(bR2, 32); bR3 += __shfl_xor(bR3, 32);

    // epilogue: bias + residual + LN over features 4j..4j+3 (32-lane groups, both halves identical)
    int f0i = 4 * j;
    float4 xr  = *(const float4*)&x[(size_t)node * 128 + f0i];
    float4 lbi = *(const float4*)&loc_bias[f0i];
    float4 rbi = *(const float4*)&reg_bias[f0i];
    float v0 = aL0 * iA + lbi.x + xr.x;
    float v1 = aL1 * iA + lbi.y + xr.y;
    float v2 = aL2 * iA + lbi.z + xr.z;
    float v3 = aL3 * iA + lbi.w + xr.w;
    float u0 = bR0 * iB + rbi.x + xr.x;
    float u1 = bR1 * iB + rbi.y + xr.y;
    float u2 = bR2 * iB + rbi.z + xr.z;
    float u3 = bR3 * iB + rbi.w + xr.w;

    float sv = v0 + v1 + v2 + v3, su = u0 + u1 + u2 + u3;
#pragma unroll
    for (int off = 16; off; off >>= 1) { sv += __shfl_xor(sv, off); su += __shfl_xor(su, off); }
    float mv = sv * (1.f / 128.f), mu = su * (1.f / 128.f);
    float dv0 = v0 - mv, dv1 = v1 - mv, dv2 = v2 - mv, dv3 = v3 - mv;
    float du0 = u0 - mu, du1 = u1 - mu, du2 = u2 - mu, du3 = u3 - mu;
    float qv = dv0 * dv0 + dv1 * dv1 + dv2 * dv2 + dv3 * dv3;
    float qu = du0 * du0 + du1 * du1 + du2 * du2 + du3 * du3;
#pragma unroll
    for (int off = 16; off; off >>= 1) { qv += __shfl_xor(qv, off); qu += __shfl_xor(qu, off); }
    float rv = rsqrtf(qv * (1.f / 128.f) + 1e-5f), ru = rsqrtf(qu * (1.f / 128.f) + 1e-5f);
    if (half == 0) {
        float4 lg = *(const float4*)&loc_g[f0i], lb2 = *(const float4*)&loc_b[f0i];
        float4 rg = *(const float4*)&reg_g[f0i], rb2 = *(const float4*)&reg_b[f0i];
        uint2 pv, pu;
        pv.x = (unsigned)f2b(dv0 * rv * lg.x + lb2.x) | ((unsigned)f2b(dv1 * rv * lg.y + lb2.y) << 16);
        pv.y = (unsigned)f2b(dv2 * rv * lg.z + lb2.z) | ((unsigned)f2b(dv3 * rv * lg.w + lb2.w) << 16);
        pu.x = (unsigned)f2b(du0 * ru * rg.x + rb2.x) | ((unsigned)f2b(du1 * ru * rg.y + rb2.y) << 16);
        pu.y = (unsigned)f2b(du2 * ru * rg.z + rb2.z) | ((unsigned)f2b(du3 * ru * rg.w + rb2.w) << 16);
        *(uint2*)&out_local[(size_t)node * 128 + f0i] = pv;
        *(uint2*)&out_reg[(size_t)node * 128 + f0i]   = pu;
    }
}

// ---------------- fused MLP (MFMA) ----------------
__global__ __launch_bounds__(256) void k_fusedm(
    const unsigned short* __restrict__ localb, const unsigned short* __restrict__ regionalb,
    const unsigned short* __restrict__ g8b, const int* __restrict__ batch,
    const unsigned short* __restrict__ W1t, const float* __restrict__ b1,
    const unsigned short* __restrict__ W2t, const float* __restrict__ b2,
    const float* __restrict__ lng, const float* __restrict__ lnb,
    float* __restrict__ out) {
    __shared__ unsigned short As[4 * 64 * 8];
    __shared__ unsigned short Bs[4 * 256 * 8];
    __shared__ unsigned short Hs[32 * 64 * 8];
    __shared__ unsigned short W2s[4 * 128 * 8];
    int t = threadIdx.x;
    int w = t >> 6, l = t & 63;
    int lq = l >> 4, lr = l & 15;
    int r0 = blockIdx.x * 64;

    int srow = t >> 2, sg = t & 3;
    int snode = r0 + srow; if (snode >= NN) snode = NN - 1;
    int sbatch = batch[snode];

    f4v acc[4][4];
#pragma unroll
    for (int a0 = 0; a0 < 4; a0++)
#pragma unroll
        for (int b0 = 0; b0 < 4; b0++) acc[a0][b0] = (f4v){0.f, 0.f, 0.f, 0.f};

    for (int ks = 0; ks < 12; ++ks) {
        int seg = ks >> 2;
        int ko = (ks & 3) * 32 + sg * 8;
        const unsigned short* src =
            seg == 0 ? localb + (size_t)snode * 128 + ko :
            seg == 1 ? regionalb + (size_t)snode * 128 + ko :
                       g8b + (size_t)sbatch * 128 + ko;
        *(s8v*)&As[(sg * 64 + srow) * 8] = *(const s8v*)src;
#pragma unroll
        for (int it = 0; it < 4; ++it) {
            int c = t + it * 256;
            int g = c & 3, n = c >> 2;
            *(s8v*)&Bs[(g * 256 + n) * 8] = *(const s8v*)&W1t[(size_t)n * 384 + ks * 32 + g * 8];
        }
        __syncthreads();
        s8v af[4], bf[4];
#pragma unroll
        for (int rf = 0; rf < 4; ++rf) af[rf] = *(const s8v*)&As[(lq * 64 + rf * 16 + lr) * 8];
#pragma unroll
        for (int cf = 0; cf < 4; ++cf) bf[cf] = *(const s8v*)&Bs[(lq * 256 + w * 64 + cf * 16 + lr) * 8];
#pragma unroll
        for (int rf = 0; rf < 4; ++rf)
#pragma unroll
            for (int cf = 0; cf < 4; ++cf)
                acc[rf][cf] = __builtin_amdgcn_mfma_f32_16x16x32_bf16(af[rf], bf[cf], acc[rf][cf], 0, 0, 0);
        __syncthreads();
    }
#pragma unroll
    for (int cf = 0; cf < 4; ++cf) {
        int c = w * 64 + cf * 16 + lr;
        float bc = b1[c];
#pragma unroll
        for (int rf = 0; rf < 4; ++rf)
#pragma unroll
            for (int i = 0; i < 4; ++i) {
                int row = rf * 16 + lq * 4 + i;
                float v0 = acc[rf][cf][i] + bc;
                Hs[((c >> 3) * 64 + row) * 8 + (c & 7)] = f2b(v0 > 0.f ? v0 : 0.f);
            }
    }
    __syncthreads();
    f4v a2[8];
#pragma unroll
    for (int cf = 0; cf < 8; ++cf) a2[cf] = (f4v){0.f, 0.f, 0.f, 0.f};
    for (int ks = 0; ks < 8; ++ks) {
#pragma unroll
        for (int it = 0; it < 2; ++it) {
            int c = t + it * 256;
            int g = c & 3, n = c >> 2;
            *(s8v*)&W2s[(g * 128 + n) * 8] = *(const s8v*)&W2t[(size_t)n * 256 + ks * 32 + g * 8];
        }
        __syncthreads();
        s8v af = *(const s8v*)&Hs[((ks * 4 + lq) * 64 + w * 16 + lr) * 8];
#pragma unroll
        for (int cf = 0; cf < 8; ++cf) {
            s8v bfv = *(const s8v*)&W2s[(lq * 128 + cf * 16 + lr) * 8];
            a2[cf] = __builtin_amdgcn_mfma_f32_16x16x32_bf16(af, bfv, a2[cf], 0, 0, 0);
        }
        __syncthreads();
    }
    float b2c[8], gc[8], bc2[8];
#pragma unroll
    for (int cf = 0; cf < 8; ++cf) {
        int c = cf * 16 + lr;
        b2c[cf] = b2[c]; gc[cf] = lng[c]; bc2[cf] = lnb[c];
    }
#pragma unroll
    for (int i = 0; i < 4; ++i) {
        int row = w * 16 + lq * 4 + i;
        int node = r0 + row;
        float vals[8]; float s = 0.f;
#pragma unroll
        for (int cf = 0; cf < 8; ++cf) { vals[cf] = a2[cf][i] + b2c[cf]; s += vals[cf]; }
        s += __shfl_xor(s, 1); s += __shfl_xor(s, 2); s += __shfl_xor(s, 4); s += __shfl_xor(s, 8);
        float mean = s * (1.f / 128.f);
        float vs = 0.f;
#pragma unroll
        for (int cf = 0; cf < 8; ++cf) { float d = vals[cf] - mean; vs += d * d; }
        vs += __shfl_xor(vs, 1); vs += __shfl_xor(vs, 2); vs += __shfl_xor(vs, 4); vs += __shfl_xor(vs, 8);
        float rstd = rsqrtf(vs * (1.f / 128.f) + 1e-5f);
        if (node < NN) {
#pragma unroll
            for (int cf = 0; cf < 8; ++cf)
                out[(size_t)node * 128 + cf * 16 + lr] = (vals[cf] - mean) * rstd * gc[cf] + bc2[cf];
        }
    }
}

extern "C" void kernel_launch(void* const* d_in, const int* in_sizes, int n_in,
                              void* d_out, int out_size, void* d_ws, size_t ws_size,
                              hipStream_t stream) {
    const float* x      = (const float*)d_in[0];
    const int*   ei     = (const int*)d_in[1];
    const int*   batch  = (const int*)d_in[2];
    const float* locW   = (const float*)d_in[3];
    const float* loc_as = (const float*)d_in[4];
    const float* loc_ad = (const float*)d_in[5];
    const float* loc_bi = (const float*)d_in[6];
    const float* loc_g  = (const float*)d_in[7];
    const float* loc_b  = (const float*)d_in[8];
    const float* regW   = (const float*)d_in[9];
    const float* reg_as = (const float*)d_in[10];
    const float* reg_ad = (const float*)d_in[11];
    const float* reg_bi = (const float*)d_in[12];
    const float* reg_g  = (const float*)d_in[13];
    const float* reg_b  = (const float*)d_in[14];
    const float* gp_W1  = (const float*)d_in[15];
    const float* gp_b1  = (const float*)d_in[16];
    const float* gp_W2  = (const float*)d_in[17];
    const float* gp_b2  = (const float*)d_in[18];
    const float* fu_W1  = (const float*)d_in[19];
    const float* fu_b1  = (const float*)d_in[20];
    const float* fu_W2  = (const float*)d_in[21];
    const float* fu_b2  = (const float*)d_in[22];
    const float* fu_lg  = (const float*)d_in[23];
    const float* fu_lb  = (const float*)d_in[24];
    float* out = (float*)d_out;

    char* ws = (char*)d_ws;
    size_t off = 0;
    auto alloc = [&](size_t bytes) { void* p = ws + off; off += (bytes + 255) & ~(size_t)255; return p; };
    unsigned* hc              = (unsigned*)alloc((size_t)NN * 128 * 4);
    unsigned short* localb    = (unsigned short*)alloc((size_t)NN * 128 * 2);
    unsigned short* regionalb = (unsigned short*)alloc((size_t)NN * 128 * 2);
    float* als_l  = (float*)alloc((size_t)NN * 4 * 4);
    float* ald_l  = (float*)alloc((size_t)NN * 4 * 4);
    float* als_r  = (float*)alloc((size_t)NN * 4 * 4);
    float* ald_r  = (float*)alloc((size_t)NN * 4 * 4);
    int* row_ptr  = (int*)alloc((size_t)(NN + 1) * 4);
    int* cur      = (int*)alloc((size_t)NN * 4);
    int* col      = (int*)alloc((size_t)(EE + NN) * 4);
    float* pooled = (float*)alloc((size_t)BB * 128 * 4);
    unsigned short* g8b = (unsigned short*)alloc((size_t)BB * 128 * 2);
    unsigned short* Wt  = (unsigned short*)alloc((size_t)32768 * 2);
    unsigned short* W1t = (unsigned short*)alloc((size_t)98304 * 2);
    unsigned short* W2t = (unsigned short*)alloc((size_t)32768 * 2);
    int* bsum = (int*)alloc((size_t)NBLK * 4);
    int* boff = (int*)alloc((size_t)NBLK * 4);

    // prep covers: 640 blocks conv + 196 blocks init
    hipLaunchKernelGGL(k_prep, dim3(640 + NBLK), dim3(256), 0, stream,
                       locW, regW, fu_W1, fu_W2, Wt, W1t, W2t, cur, pooled);
    hipLaunchKernelGGL(k_count, dim3((EE + 255) / 256), dim3(256), 0, stream, ei, cur);
    hipLaunchKernelGGL(k_scanA, dim3(NBLK), dim3(256), 0, stream, cur, row_ptr, bsum);
    hipLaunchKernelGGL(k_scanB, dim3(1), dim3(256), 0, stream, bsum, boff);
    hipLaunchKernelGGL(k_scanC, dim3(NBLK), dim3(256), 0, stream, row_ptr, boff);
    hipLaunchKernelGGL(k_scatter, dim3((EE + NN + 255) / 256), dim3(256), 0, stream, ei, row_ptr, cur, col);
    hipLaunchKernelGGL(k_gemm1, dim3((NN + 63) / 64), dim3(256), 0, stream,
                       x, Wt, loc_as, loc_ad, reg_as, reg_ad,
                       hc, als_l, ald_l, als_r, ald_r);
    hipLaunchKernelGGL(k_pool, dim3((NN + 255) / 256), dim3(256), 0, stream, x, batch, pooled);
    hipLaunchKernelGGL(k_gfeat8, dim3(BB), dim3(256), 0, stream,
                       pooled, batch, gp_W1, gp_b1, gp_W2, gp_b2, g8b);
    hipLaunchKernelGGL(k_gat, dim3(NN / 4), dim3(256), 0, stream,
                       row_ptr, col, hc, als_l, ald_l, als_r, ald_r, x,
                       loc_bi, loc_g, loc_b, reg_bi, reg_g, reg_b,
                       localb, regionalb);
    hipLaunchKernelGGL(k_fusedm, dim3((NN + 63) / 64), dim3(256), 0, stream,
                       localb, regionalb, g8b, batch,
                       W1t, fu_b1, W2t, fu_b2, fu_lg, fu_lb, out);
}

// Round 10
// 275.693 us; speedup vs baseline: 1.1493x; 1.1292x over previous
//
#include <hip/hip_runtime.h>

#define NN 50000
#define EE 800000
#define FF 128
#define HH 4
#define BB 8
#define NEG 0.2f
#define NBLK ((NN + 255) / 256)   // 196

typedef __attribute__((ext_vector_type(8))) short s8v;
typedef __attribute__((ext_vector_type(4))) float f4v;

__device__ __forceinline__ unsigned short f2b(float f) {
    union { float f; unsigned u; } v; v.f = f;
    unsigned r = v.u + 0x7fffu + ((v.u >> 16) & 1u);
    return (unsigned short)(r >> 16);
}
__device__ __forceinline__ float b2f(unsigned short h) {
    union { unsigned u; float f; } v; v.u = ((unsigned)h) << 16;
    return v.f;
}
__device__ __forceinline__ float uasf(unsigned u) {
    union { unsigned u; float f; } v; v.u = u; return v.f;
}
__device__ __forceinline__ float lrelu(float t) { return t > 0.f ? t : NEG * t; }

// ---------------- prep: weight transpose/convert + cur=1 + pooled=0 ----------------
__global__ void k_prep(const float* __restrict__ locW, const float* __restrict__ regW,
                       const float* __restrict__ W1, const float* __restrict__ W2,
                       unsigned short* __restrict__ Wt, unsigned short* __restrict__ W1t,
                       unsigned short* __restrict__ W2t, int* cur, float* pooled) {
    int i = blockIdx.x * 256 + threadIdx.x;
    if (i < 32768) {
        int n = i >> 7, k = i & 127;
        float v = n < 128 ? locW[k * 128 + n] : regW[k * 128 + n - 128];
        Wt[i] = f2b(v);
    } else if (i < 131072) {
        int j = i - 32768; int n = j / 384, k = j - n * 384;
        W1t[j] = f2b(W1[k * 256 + n]);
    } else if (i < 163840) {
        int j = i - 131072; int n = j >> 8, k = j & 255;
        W2t[j] = f2b(W2[k * 128 + n]);
    } else {
        int j = i - 163840;
        if (j < NN) cur[j] = 1;
        if (j < BB * FF) pooled[j] = 0.f;
    }
}

// ---------------- count in-degree ----------------
__global__ void k_count(const int* __restrict__ ei, int* cur) {
    int i = blockIdx.x * 256 + threadIdx.x;
    if (i < EE) atomicAdd(&cur[ei[EE + i]], 1);
}

// ---------------- 3-phase parallel scan ----------------
__global__ __launch_bounds__(256) void k_scanA(int* cur, int* row_ptr, int* bsum) {
    __shared__ int wsum[4];
    int b = blockIdx.x, t = threadIdx.x;
    int i = b * 256 + t;
    int v = (i < NN) ? cur[i] : 0;
    if (i < NN) cur[i] = 0;
    int lane = t & 63, w = t >> 6;
    int sc = v;
#pragma unroll
    for (int off = 1; off < 64; off <<= 1) {
        int n = __shfl_up(sc, off);
        if (lane >= off) sc += n;
    }
    if (lane == 63) wsum[w] = sc;
    __syncthreads();
    int woff = 0;
    for (int k = 0; k < w; k++) woff += wsum[k];
    int incl = sc + woff;
    if (i < NN) row_ptr[i + 1] = incl;
    if (t == 255) bsum[b] = incl;
    if (i == 0) row_ptr[0] = 0;
}

__global__ __launch_bounds__(256) void k_scanB(const int* __restrict__ bsum, int* boff) {
    __shared__ int wsum[4];
    int t = threadIdx.x;
    int v = (t < NBLK) ? bsum[t] : 0;
    int lane = t & 63, w = t >> 6;
    int sc = v;
#pragma unroll
    for (int off = 1; off < 64; off <<= 1) {
        int n = __shfl_up(sc, off);
        if (lane >= off) sc += n;
    }
    if (lane == 63) wsum[w] = sc;
    __syncthreads();
    int woff = 0;
    for (int k = 0; k < w; k++) woff += wsum[k];
    if (t < NBLK) boff[t] = sc + woff - v;
}

__global__ __launch_bounds__(256) void k_scanC(int* row_ptr, const int* __restrict__ boff) {
    int i = blockIdx.x * 256 + threadIdx.x;
    if (i < NN) row_ptr[i + 1] += boff[blockIdx.x];
}

// ---------------- scatter edges (and self loops) into CSR ----------------
__global__ void k_scatter(const int* __restrict__ ei, const int* __restrict__ row_ptr,
                          int* cur, int* col) {
    int i = blockIdx.x * 256 + threadIdx.x;
    if (i < EE) {
        int s = ei[i], d = ei[EE + i];
        int p = atomicAdd(&cur[d], 1);
        col[row_ptr[d] + p] = s;
    } else if (i < EE + NN) {
        int n = i - EE;
        int p = atomicAdd(&cur[n], 1);
        col[row_ptr[n] + p] = n;
    }
}

// ---------------- GEMM1 (MFMA): h -> hl/hr; alpha -> alc_s/alc_d; fused x pooling ----------------
__global__ __launch_bounds__(256) void k_gemm1(
    const float* __restrict__ x, const int* __restrict__ batch,
    const unsigned short* __restrict__ Wt,
    const float* __restrict__ loc_as, const float* __restrict__ loc_ad,
    const float* __restrict__ reg_as, const float* __restrict__ reg_ad,
    unsigned short* __restrict__ hl, unsigned short* __restrict__ hr,
    float* __restrict__ alc_s, float* __restrict__ alc_d,
    float* __restrict__ pooled) {
    __shared__ unsigned short As[4 * 64 * 8];
    __shared__ unsigned short Bs[4 * 256 * 8];
    __shared__ unsigned short Hs[32 * 64 * 8];
    int t = threadIdx.x;
    int w = t >> 6, l = t & 63;
    int lq = l >> 4, lr = l & 15;
    int r0 = blockIdx.x * 64;

    int srow = t >> 2, sg = t & 3;
    int snode = r0 + srow; if (snode >= NN) snode = NN - 1;
    const float* xrow = x + (size_t)snode * 128 + sg * 8;

    f4v acc[4][4];
#pragma unroll
    for (int a0 = 0; a0 < 4; a0++)
#pragma unroll
        for (int b0 = 0; b0 < 4; b0++) acc[a0][b0] = (f4v){0.f, 0.f, 0.f, 0.f};

    for (int ks = 0; ks < 4; ++ks) {
        {
            float4 f0 = *(const float4*)(xrow + ks * 32);
            float4 f1 = *(const float4*)(xrow + ks * 32 + 4);
            unsigned short u[8] = { f2b(f0.x), f2b(f0.y), f2b(f0.z), f2b(f0.w),
                                    f2b(f1.x), f2b(f1.y), f2b(f1.z), f2b(f1.w) };
            *(s8v*)&As[(sg * 64 + srow) * 8] = *(const s8v*)u;
        }
#pragma unroll
        for (int it = 0; it < 4; ++it) {
            int c = t + it * 256;
            int g = c & 3, n = c >> 2;
            *(s8v*)&Bs[(g * 256 + n) * 8] = *(const s8v*)&Wt[(size_t)n * 128 + ks * 32 + g * 8];
        }
        __syncthreads();
        s8v af[4], bf[4];
#pragma unroll
        for (int rf = 0; rf < 4; ++rf) af[rf] = *(const s8v*)&As[(lq * 64 + rf * 16 + lr) * 8];
#pragma unroll
        for (int cf = 0; cf < 4; ++cf) bf[cf] = *(const s8v*)&Bs[(lq * 256 + w * 64 + cf * 16 + lr) * 8];
#pragma unroll
        for (int rf = 0; rf < 4; ++rf)
#pragma unroll
            for (int cf = 0; cf < 4; ++cf)
                acc[rf][cf] = __builtin_amdgcn_mfma_f32_16x16x32_bf16(af[rf], bf[cf], acc[rf][cf], 0, 0, 0);
        __syncthreads();
    }
#pragma unroll
    for (int cf = 0; cf < 4; ++cf) {
        int c = w * 64 + cf * 16 + lr;
#pragma unroll
        for (int rf = 0; rf < 4; ++rf)
#pragma unroll
            for (int i = 0; i < 4; ++i) {
                int row = rf * 16 + lq * 4 + i;
                Hs[((c >> 3) * 64 + row) * 8 + (c & 7)] = f2b(acc[rf][cf][i]);
            }
    }
    __syncthreads();
    // flush h -> hl/hr (coalesced 16B)
#pragma unroll
    for (int it = 0; it < 8; ++it) {
        int c = t + it * 256;
        int row = c >> 5, g = c & 31;
        int node = r0 + row;
        if (node < NN) {
            s8v v = *(const s8v*)&Hs[(g * 64 + row) * 8];
            int cc = g * 8;
            if (cc < 128) *(s8v*)&hl[(size_t)node * 128 + cc] = v;
            else          *(s8v*)&hr[(size_t)node * 128 + cc - 128] = v;
        }
    }
    // alpha epilogue: alc_s/alc_d[node*8 + gat*4 + head]
#pragma unroll
    for (int it = 0; it < 4; ++it) {
        int row = it * 16 + (t >> 4);
        int node = r0 + row;
        int q = t & 15;
        int gat = q >> 3, sd = (q >> 2) & 1, head = q & 3;
        const float* av = gat ? (sd ? reg_ad : reg_as) : (sd ? loc_ad : loc_as);
        float s = 0.f;
        int cbase = gat * 128 + head * 32;
        for (int d = 0; d < 32; ++d) {
            int c = cbase + d;
            s += b2f(Hs[((c >> 3) * 64 + row) * 8 + (c & 7)]) * av[head * 32 + d];
        }
        if (node < NN) {
            float* outp = sd ? alc_d : alc_s;
            outp[(size_t)node * 8 + gat * 4 + head] = s;
        }
    }
    // fused mean-pool partials (x tile is L2-hot; <=2 batch segments per 64-row tile)
    {
        int colp = t & 127, halfp = t >> 7;
        int rbase = r0 + halfp * 32;
        int lastrow = r0 + 63; if (lastrow >= NN) lastrow = NN - 1;
        int blo = batch[r0 < NN ? r0 : NN - 1];
        int bhi = batch[lastrow];
        float acc0 = 0.f, acc1 = 0.f;
        for (int r = 0; r < 32; ++r) {
            int row = rbase + r;
            if (row < NN) {
                float v = x[(size_t)row * 128 + colp];
                int b = batch[row];
                if (b == blo) acc0 += v; else acc1 += v;
            }
        }
        atomicAdd(&pooled[blo * 128 + colp], acc0);
        if (bhi != blo) atomicAdd(&pooled[bhi * 128 + colp], acc1);
    }
}

// ---------------- gfeat: one block per graph ----------------
__global__ __launch_bounds__(256) void k_gfeat8(
    const float* __restrict__ pooled, const int* __restrict__ batch,
    const float* __restrict__ W1, const float* __restrict__ b1,
    const float* __restrict__ W2, const float* __restrict__ b2,
    unsigned short* __restrict__ g8b) {
    __shared__ float mean_s[128];
    __shared__ float hid_s[128];
    __shared__ float part[256];
    __shared__ int bnd[2];
    int b = blockIdx.x, t = threadIdx.x;
    if (t < 2) {
        int target = b + t;
        int lo = 0, hi = NN;
        while (lo < hi) { int mid = (lo + hi) >> 1; if (batch[mid] < target) lo = mid + 1; else hi = mid; }
        bnd[t] = lo;
    }
    __syncthreads();
    int cnt = bnd[1] - bnd[0];
    float inv = cnt ? 1.f / (float)cnt : 0.f;
    if (t < 128) mean_s[t] = pooled[b * 128 + t] * inv;
    __syncthreads();
    int c = t & 127, kh = t >> 7;
    float a = 0.f;
    for (int k = kh * 64; k < kh * 64 + 64; k++) a += mean_s[k] * W1[k * 128 + c];
    part[t] = a;
    __syncthreads();
    if (t < 128) hid_s[t] = fmaxf(part[t] + part[t + 128] + b1[t], 0.f);
    __syncthreads();
    float a2 = 0.f;
    for (int k = kh * 64; k < kh * 64 + 64; k++) a2 += hid_s[k] * W2[k * 128 + c];
    part[t] = a2;
    __syncthreads();
    if (t < 128) g8b[b * 128 + t] = f2b(part[t] + part[t + 128] + b2[t]);
}

// ---------------- GAT aggregate (R5 structure): packed 2-feat/lane, interleaved alc ----------------
__global__ __launch_bounds__(256) void k_gat(
    const int* __restrict__ row_ptr, const int* __restrict__ col,
    const unsigned short* __restrict__ hl, const unsigned short* __restrict__ hr,
    const float* __restrict__ alc_s, const float* __restrict__ alc_d,
    const float* __restrict__ x,
    const float* __restrict__ loc_bias, const float* __restrict__ loc_g, const float* __restrict__ loc_b,
    const float* __restrict__ reg_bias, const float* __restrict__ reg_g, const float* __restrict__ reg_b,
    unsigned short* __restrict__ out_local, unsigned short* __restrict__ out_reg) {
    __shared__ float exA[4][64][4];
    __shared__ float exB[4][64][4];
    __shared__ int   colb[4][64];
    __shared__ int   degs[4];
    int w = threadIdx.x >> 6, lane = threadIdx.x & 63;
    int hA = lane >> 4;                 // head of features {2*lane, 2*lane+1}
    int node = blockIdx.x * 4 + w;
    int rp0 = row_ptr[node];
    int deg = row_ptr[node + 1] - rp0;
    if (lane == 0) degs[w] = deg;
    float4 adL = *(const float4*)&alc_d[(size_t)node * 8];
    float4 adR = *(const float4*)&alc_d[(size_t)node * 8 + 4];
    __syncthreads();
    int maxdeg = max(max(degs[0], degs[1]), max(degs[2], degs[3]));
    int chunks = (maxdeg + 63) >> 6;

    // sweep: lane-parallel exp + sums (LDS stage valid for serial use iff chunks==1)
    float sL0 = 0.f, sL1 = 0.f, sL2 = 0.f, sL3 = 0.f;
    float sR0 = 0.f, sR1 = 0.f, sR2 = 0.f, sR3 = 0.f;
    for (int base = 0; base < deg; base += 64) {
        int i = base + lane;
        bool v = i < deg;
        int s = col[rp0 + (v ? i : deg - 1)];
        float4 aL = *(const float4*)&alc_s[(size_t)s * 8];
        float4 aR = *(const float4*)&alc_s[(size_t)s * 8 + 4];
        float e0 = __expf(lrelu(aL.x + adL.x));
        float e1 = __expf(lrelu(aL.y + adL.y));
        float e2 = __expf(lrelu(aL.z + adL.z));
        float e3 = __expf(lrelu(aL.w + adL.w));
        float f0 = __expf(lrelu(aR.x + adR.x));
        float f1 = __expf(lrelu(aR.y + adR.y));
        float f2 = __expf(lrelu(aR.z + adR.z));
        float f3 = __expf(lrelu(aR.w + adR.w));
        if (!v) { e0 = e1 = e2 = e3 = f0 = f1 = f2 = f3 = 0.f; }
        *(float4*)&exA[w][lane][0] = make_float4(e0, e1, e2, e3);
        *(float4*)&exB[w][lane][0] = make_float4(f0, f1, f2, f3);
        colb[w][lane] = s;
        sL0 += e0; sL1 += e1; sL2 += e2; sL3 += e3;
        sR0 += f0; sR1 += f1; sR2 += f2; sR3 += f3;
    }
    __syncthreads();
#pragma unroll
    for (int off = 32; off; off >>= 1) {
        sL0 += __shfl_xor(sL0, off); sL1 += __shfl_xor(sL1, off);
        sL2 += __shfl_xor(sL2, off); sL3 += __shfl_xor(sL3, off);
        sR0 += __shfl_xor(sR0, off); sR1 += __shfl_xor(sR1, off);
        sR2 += __shfl_xor(sR2, off); sR3 += __shfl_xor(sR3, off);
    }
    float iA = (hA & 2) ? ((hA & 1) ? 1.f / sL3 : 1.f / sL2)
                        : ((hA & 1) ? 1.f / sL1 : 1.f / sL0);
    float iB = (hA & 2) ? ((hA & 1) ? 1.f / sR3 : 1.f / sR2)
                        : ((hA & 1) ? 1.f / sR1 : 1.f / sR0);

    float a0 = 0.f, a1 = 0.f, b0 = 0.f, b1 = 0.f;
    const unsigned* hlp = (const unsigned*)hl;
    const unsigned* hrp = (const unsigned*)hr;
    if (chunks == 1) {
#pragma unroll 4
        for (int e = 0; e < deg; ++e) {
            int s = colb[w][e];
            float eAv = exA[w][e][hA];
            float eBv = exB[w][e][hA];
            unsigned ul = hlp[(size_t)s * 64 + lane];
            unsigned ur = hrp[(size_t)s * 64 + lane];
            a0 += eAv * uasf(ul << 16);
            a1 += eAv * uasf(ul & 0xffff0000u);
            b0 += eBv * uasf(ur << 16);
            b1 += eBv * uasf(ur & 0xffff0000u);
        }
    } else {
        for (int c = 0; c < chunks; ++c) {
            int base = c * 64, i = base + lane;
            if (i < deg) {
                int s = col[rp0 + i];
                float4 aL = *(const float4*)&alc_s[(size_t)s * 8];
                float4 aR = *(const float4*)&alc_s[(size_t)s * 8 + 4];
                *(float4*)&exA[w][lane][0] = make_float4(
                    __expf(lrelu(aL.x + adL.x)), __expf(lrelu(aL.y + adL.y)),
                    __expf(lrelu(aL.z + adL.z)), __expf(lrelu(aL.w + adL.w)));
                *(float4*)&exB[w][lane][0] = make_float4(
                    __expf(lrelu(aR.x + adR.x)), __expf(lrelu(aR.y + adR.y)),
                    __expf(lrelu(aR.z + adR.z)), __expf(lrelu(aR.w + adR.w)));
                colb[w][lane] = s;
            }
            __syncthreads();
            int nc = deg - base; nc = nc < 0 ? 0 : (nc > 64 ? 64 : nc);
#pragma unroll 4
            for (int e = 0; e < nc; ++e) {
                int s = colb[w][e];
                float eAv = exA[w][e][hA];
                float eBv = exB[w][e][hA];
                unsigned ul = hlp[(size_t)s * 64 + lane];
                unsigned ur = hrp[(size_t)s * 64 + lane];
                a0 += eAv * uasf(ul << 16);
                a1 += eAv * uasf(ul & 0xffff0000u);
                b0 += eBv * uasf(ur << 16);
                b1 += eBv * uasf(ur & 0xffff0000u);
            }
            __syncthreads();
        }
    }

    // epilogue: bias + residual + LN (features 2*lane, 2*lane+1)
    int f = 2 * lane;
    float2 xr = *(const float2*)&x[(size_t)node * 128 + f];
    float2 lbi = *(const float2*)&loc_bias[f];
    float2 rbi = *(const float2*)&reg_bias[f];
    float v0 = a0 * iA + lbi.x + xr.x;
    float v1 = a1 * iA + lbi.y + xr.y;
    float u0 = b0 * iB + rbi.x + xr.x;
    float u1 = b1 * iB + rbi.y + xr.y;

    float sv = v0 + v1, su = u0 + u1;
#pragma unroll
    for (int off = 32; off; off >>= 1) { sv += __shfl_xor(sv, off); su += __shfl_xor(su, off); }
    float mv = sv * (1.f / 128.f), mu = su * (1.f / 128.f);
    float dv0 = v0 - mv, dv1 = v1 - mv, du0 = u0 - mu, du1 = u1 - mu;
    float qv = dv0 * dv0 + dv1 * dv1, qu = du0 * du0 + du1 * du1;
#pragma unroll
    for (int off = 32; off; off >>= 1) { qv += __shfl_xor(qv, off); qu += __shfl_xor(qu, off); }
    float rv = rsqrtf(qv * (1.f / 128.f) + 1e-5f), ru = rsqrtf(qu * (1.f / 128.f) + 1e-5f);
    float2 lg = *(const float2*)&loc_g[f], lb2 = *(const float2*)&loc_b[f];
    float2 rg = *(const float2*)&reg_g[f], rb2 = *(const float2*)&reg_b[f];
    unsigned pv = (unsigned)f2b(dv0 * rv * lg.x + lb2.x) | ((unsigned)f2b(dv1 * rv * lg.y + lb2.y) << 16);
    unsigned pu = (unsigned)f2b(du0 * ru * rg.x + rb2.x) | ((unsigned)f2b(du1 * ru * rg.y + rb2.y) << 16);
    *(unsigned*)&out_local[(size_t)node * 128 + f] = pv;
    *(unsigned*)&out_reg[(size_t)node * 128 + f]   = pu;
}

// ---------------- fused MLP (MFMA) ----------------
__global__ __launch_bounds__(256) void k_fusedm(
    const unsigned short* __restrict__ localb, const unsigned short* __restrict__ regionalb,
    const unsigned short* __restrict__ g8b, const int* __restrict__ batch,
    const unsigned short* __restrict__ W1t, const float* __restrict__ b1,
    const unsigned short* __restrict__ W2t, const float* __restrict__ b2,
    const float* __restrict__ lng, const float* __restrict__ lnb,
    float* __restrict__ out) {
    __shared__ unsigned short As[4 * 64 * 8];
    __shared__ unsigned short Bs[4 * 256 * 8];
    __shared__ unsigned short Hs[32 * 64 * 8];
    __shared__ unsigned short W2s[4 * 128 * 8];
    int t = threadIdx.x;
    int w = t >> 6, l = t & 63;
    int lq = l >> 4, lr = l & 15;
    int r0 = blockIdx.x * 64;

    int srow = t >> 2, sg = t & 3;
    int snode = r0 + srow; if (snode >= NN) snode = NN - 1;
    int sbatch = batch[snode];

    f4v acc[4][4];
#pragma unroll
    for (int a0 = 0; a0 < 4; a0++)
#pragma unroll
        for (int b0 = 0; b0 < 4; b0++) acc[a0][b0] = (f4v){0.f, 0.f, 0.f, 0.f};

    for (int ks = 0; ks < 12; ++ks) {
        int seg = ks >> 2;
        int ko = (ks & 3) * 32 + sg * 8;
        const unsigned short* src =
            seg == 0 ? localb + (size_t)snode * 128 + ko :
            seg == 1 ? regionalb + (size_t)snode * 128 + ko :
                       g8b + (size_t)sbatch * 128 + ko;
        *(s8v*)&As[(sg * 64 + srow) * 8] = *(const s8v*)src;
#pragma unroll
        for (int it = 0; it < 4; ++it) {
            int c = t + it * 256;
            int g = c & 3, n = c >> 2;
            *(s8v*)&Bs[(g * 256 + n) * 8] = *(const s8v*)&W1t[(size_t)n * 384 + ks * 32 + g * 8];
        }
        __syncthreads();
        s8v af[4], bf[4];
#pragma unroll
        for (int rf = 0; rf < 4; ++rf) af[rf] = *(const s8v*)&As[(lq * 64 + rf * 16 + lr) * 8];
#pragma unroll
        for (int cf = 0; cf < 4; ++cf) bf[cf] = *(const s8v*)&Bs[(lq * 256 + w * 64 + cf * 16 + lr) * 8];
#pragma unroll
        for (int rf = 0; rf < 4; ++rf)
#pragma unroll
            for (int cf = 0; cf < 4; ++cf)
                acc[rf][cf] = __builtin_amdgcn_mfma_f32_16x16x32_bf16(af[rf], bf[cf], acc[rf][cf], 0, 0, 0);
        __syncthreads();
    }
#pragma unroll
    for (int cf = 0; cf < 4; ++cf) {
        int c = w * 64 + cf * 16 + lr;
        float bc = b1[c];
#pragma unroll
        for (int rf = 0; rf < 4; ++rf)
#pragma unroll
            for (int i = 0; i < 4; ++i) {
                int row = rf * 16 + lq * 4 + i;
                float v0 = acc[rf][cf][i] + bc;
                Hs[((c >> 3) * 64 + row) * 8 + (c & 7)] = f2b(v0 > 0.f ? v0 : 0.f);
            }
    }
    __syncthreads();
    f4v a2[8];
#pragma unroll
    for (int cf = 0; cf < 8; ++cf) a2[cf] = (f4v){0.f, 0.f, 0.f, 0.f};
    for (int ks = 0; ks < 8; ++ks) {
#pragma unroll
        for (int it = 0; it < 2; ++it) {
            int c = t + it * 256;
            int g = c & 3, n = c >> 2;
            *(s8v*)&W2s[(g * 128 + n) * 8] = *(const s8v*)&W2t[(size_t)n * 256 + ks * 32 + g * 8];
        }
        __syncthreads();
        s8v af = *(const s8v*)&Hs[((ks * 4 + lq) * 64 + w * 16 + lr) * 8];
#pragma unroll
        for (int cf = 0; cf < 8; ++cf) {
            s8v bfv = *(const s8v*)&W2s[(lq * 128 + cf * 16 + lr) * 8];
            a2[cf] = __builtin_amdgcn_mfma_f32_16x16x32_bf16(af, bfv, a2[cf], 0, 0, 0);
        }
        __syncthreads();
    }
    float b2c[8], gc[8], bc2[8];
#pragma unroll
    for (int cf = 0; cf < 8; ++cf) {
        int c = cf * 16 + lr;
        b2c[cf] = b2[c]; gc[cf] = lng[c]; bc2[cf] = lnb[c];
    }
#pragma unroll
    for (int i = 0; i < 4; ++i) {
        int row = w * 16 + lq * 4 + i;
        int node = r0 + row;
        float vals[8]; float s = 0.f;
#pragma unroll
        for (int cf = 0; cf < 8; ++cf) { vals[cf] = a2[cf][i] + b2c[cf]; s += vals[cf]; }
        s += __shfl_xor(s, 1); s += __shfl_xor(s, 2); s += __shfl_xor(s, 4); s += __shfl_xor(s, 8);
        float mean = s * (1.f / 128.f);
        float vs = 0.f;
#pragma unroll
        for (int cf = 0; cf < 8; ++cf) { float d = vals[cf] - mean; vs += d * d; }
        vs += __shfl_xor(vs, 1); vs += __shfl_xor(vs, 2); vs += __shfl_xor(vs, 4); vs += __shfl_xor(vs, 8);
        float rstd = rsqrtf(vs * (1.f / 128.f) + 1e-5f);
        if (node < NN) {
#pragma unroll
            for (int cf = 0; cf < 8; ++cf)
                out[(size_t)node * 128 + cf * 16 + lr] = (vals[cf] - mean) * rstd * gc[cf] + bc2[cf];
        }
    }
}

extern "C" void kernel_launch(void* const* d_in, const int* in_sizes, int n_in,
                              void* d_out, int out_size, void* d_ws, size_t ws_size,
                              hipStream_t stream) {
    const float* x      = (const float*)d_in[0];
    const int*   ei     = (const int*)d_in[1];
    const int*   batch  = (const int*)d_in[2];
    const float* locW   = (const float*)d_in[3];
    const float* loc_as = (const float*)d_in[4];
    const float* loc_ad = (const float*)d_in[5];
    const float* loc_bi = (const float*)d_in[6];
    const float* loc_g  = (const float*)d_in[7];
    const float* loc_b  = (const float*)d_in[8];
    const float* regW   = (const float*)d_in[9];
    const float* reg_as = (const float*)d_in[10];
    const float* reg_ad = (const float*)d_in[11];
    const float* reg_bi = (const float*)d_in[12];
    const float* reg_g  = (const float*)d_in[13];
    const float* reg_b  = (const float*)d_in[14];
    const float* gp_W1  = (const float*)d_in[15];
    const float* gp_b1  = (const float*)d_in[16];
    const float* gp_W2  = (const float*)d_in[17];
    const float* gp_b2  = (const float*)d_in[18];
    const float* fu_W1  = (const float*)d_in[19];
    const float* fu_b1  = (const float*)d_in[20];
    const float* fu_W2  = (const float*)d_in[21];
    const float* fu_b2  = (const float*)d_in[22];
    const float* fu_lg  = (const float*)d_in[23];
    const float* fu_lb  = (const float*)d_in[24];
    float* out = (float*)d_out;

    char* ws = (char*)d_ws;
    size_t off = 0;
    auto alloc = [&](size_t bytes) { void* p = ws + off; off += (bytes + 255) & ~(size_t)255; return p; };
    unsigned short* hl        = (unsigned short*)alloc((size_t)NN * 128 * 2);
    unsigned short* hr        = (unsigned short*)alloc((size_t)NN * 128 * 2);
    unsigned short* localb    = (unsigned short*)alloc((size_t)NN * 128 * 2);
    unsigned short* regionalb = (unsigned short*)alloc((size_t)NN * 128 * 2);
    float* alc_s  = (float*)alloc((size_t)NN * 8 * 4);
    float* alc_d  = (float*)alloc((size_t)NN * 8 * 4);
    int* row_ptr  = (int*)alloc((size_t)(NN + 1) * 4);
    int* cur      = (int*)alloc((size_t)NN * 4);
    int* col      = (int*)alloc((size_t)(EE + NN) * 4);
    float* pooled = (float*)alloc((size_t)BB * 128 * 4);
    unsigned short* g8b = (unsigned short*)alloc((size_t)BB * 128 * 2);
    unsigned short* Wt  = (unsigned short*)alloc((size_t)32768 * 2);
    unsigned short* W1t = (unsigned short*)alloc((size_t)98304 * 2);
    unsigned short* W2t = (unsigned short*)alloc((size_t)32768 * 2);
    int* bsum = (int*)alloc((size_t)NBLK * 4);
    int* boff = (int*)alloc((size_t)NBLK * 4);

    hipLaunchKernelGGL(k_prep, dim3(640 + NBLK), dim3(256), 0, stream,
                       locW, regW, fu_W1, fu_W2, Wt, W1t, W2t, cur, pooled);
    hipLaunchKernelGGL(k_count, dim3((EE + 255) / 256), dim3(256), 0, stream, ei, cur);
    hipLaunchKernelGGL(k_scanA, dim3(NBLK), dim3(256), 0, stream, cur, row_ptr, bsum);
    hipLaunchKernelGGL(k_scanB, dim3(1), dim3(256), 0, stream, bsum, boff);
    hipLaunchKernelGGL(k_scanC, dim3(NBLK), dim3(256), 0, stream, row_ptr, boff);
    hipLaunchKernelGGL(k_scatter, dim3((EE + NN + 255) / 256), dim3(256), 0, stream, ei, row_ptr, cur, col);
    hipLaunchKernelGGL(k_gemm1, dim3((NN + 63) / 64), dim3(256), 0, stream,
                       x, batch, Wt, loc_as, loc_ad, reg_as, reg_ad,
                       hl, hr, alc_s, alc_d, pooled);
    hipLaunchKernelGGL(k_gfeat8, dim3(BB), dim3(256), 0, stream,
                       pooled, batch, gp_W1, gp_b1, gp_W2, gp_b2, g8b);
    hipLaunchKernelGGL(k_gat, dim3(NN / 4), dim3(256), 0, stream,
                       row_ptr, col, hl, hr, alc_s, alc_d, x,
                       loc_bi, loc_g, loc_b, reg_bi, reg_g, reg_b,
                       localb, regionalb);
    hipLaunchKernelGGL(k_fusedm, dim3((NN + 63) / 64), dim3(256), 0, stream,
                       localb, regionalb, g8b, batch,
                       W1t, fu_b1, W2t, fu_b2, fu_lg, fu_lb, out);
}

// Round 11
// 273.102 us; speedup vs baseline: 1.1602x; 1.0095x over previous
//
#include <hip/hip_runtime.h>

#define NN 50000
#define EE 800000
#define FF 128
#define HH 4
#define BB 8
#define NEG 0.2f
#define NBLK ((NN + 255) / 256)   // 196

typedef __attribute__((ext_vector_type(8))) short s8v;
typedef __attribute__((ext_vector_type(4))) float f4v;

__device__ __forceinline__ unsigned short f2b(float f) {
    union { float f; unsigned u; } v; v.f = f;
    unsigned r = v.u + 0x7fffu + ((v.u >> 16) & 1u);
    return (unsigned short)(r >> 16);
}
__device__ __forceinline__ float b2f(unsigned short h) {
    union { unsigned u; float f; } v; v.u = ((unsigned)h) << 16;
    return v.f;
}
__device__ __forceinline__ float uasf(unsigned u) {
    union { unsigned u; float f; } v; v.u = u; return v.f;
}
__device__ __forceinline__ float lrelu(float t) { return t > 0.f ? t : NEG * t; }
__device__ __forceinline__ s8v cvt8(const float* p) {
    float4 f0 = *(const float4*)p;
    float4 f1 = *(const float4*)(p + 4);
    unsigned short u[8] = { f2b(f0.x), f2b(f0.y), f2b(f0.z), f2b(f0.w),
                            f2b(f1.x), f2b(f1.y), f2b(f1.z), f2b(f1.w) };
    return *(const s8v*)u;
}

// ---------------- prep: weight transpose/convert + cur=1 + pooled=0 ----------------
__global__ void k_prep(const float* __restrict__ locW, const float* __restrict__ regW,
                       const float* __restrict__ W1, const float* __restrict__ W2,
                       unsigned short* __restrict__ Wt, unsigned short* __restrict__ W1t,
                       unsigned short* __restrict__ W2t, int* cur, float* pooled) {
    int i = blockIdx.x * 256 + threadIdx.x;
    if (i < 32768) {
        int n = i >> 7, k = i & 127;
        float v = n < 128 ? locW[k * 128 + n] : regW[k * 128 + n - 128];
        Wt[i] = f2b(v);
    } else if (i < 131072) {
        int j = i - 32768; int n = j / 384, k = j - n * 384;
        W1t[j] = f2b(W1[k * 256 + n]);
    } else if (i < 163840) {
        int j = i - 131072; int n = j >> 8, k = j & 255;
        W2t[j] = f2b(W2[k * 128 + n]);
    } else {
        int j = i - 163840;
        if (j < NN) cur[j] = 1;
        if (j < BB * FF) pooled[j] = 0.f;
    }
}

// ---------------- count in-degree ----------------
__global__ void k_count(const int* __restrict__ ei, int* cur) {
    int i = blockIdx.x * 256 + threadIdx.x;
    if (i < EE) atomicAdd(&cur[ei[EE + i]], 1);
}

// ---------------- parallel scan: A (per-block), C (offset via own reduction) ----------------
__global__ __launch_bounds__(256) void k_scanA(int* cur, int* row_ptr, int* bsum) {
    __shared__ int wsum[4];
    int b = blockIdx.x, t = threadIdx.x;
    int i = b * 256 + t;
    int v = (i < NN) ? cur[i] : 0;
    if (i < NN) cur[i] = 0;
    int lane = t & 63, w = t >> 6;
    int sc = v;
#pragma unroll
    for (int off = 1; off < 64; off <<= 1) {
        int n = __shfl_up(sc, off);
        if (lane >= off) sc += n;
    }
    if (lane == 63) wsum[w] = sc;
    __syncthreads();
    int woff = 0;
    for (int k = 0; k < w; k++) woff += wsum[k];
    int incl = sc + woff;
    if (i < NN) row_ptr[i + 1] = incl;
    if (t == 255) bsum[b] = incl;
    if (i == 0) row_ptr[0] = 0;
}

__global__ __launch_bounds__(256) void k_scanC(int* row_ptr, const int* __restrict__ bsum) {
    __shared__ int ssum[4];
    int b = blockIdx.x, t = threadIdx.x;
    int lane = t & 63, w = t >> 6;
    int v = (t < b) ? bsum[t] : 0;   // b <= 195 < 256
#pragma unroll
    for (int off = 32; off; off >>= 1) v += __shfl_xor(v, off);
    if (lane == 0) ssum[w] = v;
    __syncthreads();
    int off = ssum[0] + ssum[1] + ssum[2] + ssum[3];
    int i = b * 256 + t;
    if (i < NN && b > 0) row_ptr[i + 1] += off;
}

// ---------------- scatter edges (and self loops) into CSR ----------------
__global__ void k_scatter(const int* __restrict__ ei, const int* __restrict__ row_ptr,
                          int* cur, int* col) {
    int i = blockIdx.x * 256 + threadIdx.x;
    if (i < EE) {
        int s = ei[i], d = ei[EE + i];
        int p = atomicAdd(&cur[d], 1);
        col[row_ptr[d] + p] = s;
    } else if (i < EE + NN) {
        int n = i - EE;
        int p = atomicAdd(&cur[n], 1);
        col[row_ptr[n] + p] = n;
    }
}

// ---------------- GEMM1 (MFMA, dbuf LDS): h -> hl/hr; alpha -> alc; fused pooling ----------------
__global__ __launch_bounds__(256) void k_gemm1(
    const float* __restrict__ x, const int* __restrict__ batch,
    const unsigned short* __restrict__ Wt,
    const float* __restrict__ loc_as, const float* __restrict__ loc_ad,
    const float* __restrict__ reg_as, const float* __restrict__ reg_ad,
    unsigned short* __restrict__ hl, unsigned short* __restrict__ hr,
    float* __restrict__ alc_s, float* __restrict__ alc_d,
    float* __restrict__ pooled) {
    __shared__ __align__(16) unsigned short SA[2][2048];   // 2x 4KB
    __shared__ __align__(16) unsigned short SB[2][8192];   // 2x 16KB
    __shared__ __align__(16) unsigned short Hs[16384];     // 32KB
    int t = threadIdx.x;
    int w = t >> 6, l = t & 63;
    int lq = l >> 4, lr = l & 15;
    int r0 = blockIdx.x * 64;

    int srow = t >> 2, sg = t & 3;
    int snode = r0 + srow; if (snode >= NN) snode = NN - 1;
    const float* xrow = x + (size_t)snode * 128 + sg * 8;

    f4v acc[4][4];
#pragma unroll
    for (int a0 = 0; a0 < 4; a0++)
#pragma unroll
        for (int b0 = 0; b0 < 4; b0++) acc[a0][b0] = (f4v){0.f, 0.f, 0.f, 0.f};

    // prologue: stage ks=0
    *(s8v*)&SA[0][(sg * 64 + srow) * 8] = cvt8(xrow);
#pragma unroll
    for (int it = 0; it < 4; ++it) {
        int c = t + it * 256;
        int g = c & 3, n = c >> 2;
        *(s8v*)&SB[0][(g * 256 + n) * 8] = *(const s8v*)&Wt[(size_t)n * 128 + g * 8];
    }
    __syncthreads();
#pragma unroll
    for (int ks = 0; ks < 4; ++ks) {
        int cur = ks & 1;
        s8v pa; s8v pb[4];
        if (ks < 3) {
            pa = cvt8(xrow + (ks + 1) * 32);
#pragma unroll
            for (int it = 0; it < 4; ++it) {
                int c = t + it * 256;
                int g = c & 3, n = c >> 2;
                pb[it] = *(const s8v*)&Wt[(size_t)n * 128 + (ks + 1) * 32 + g * 8];
            }
        }
        s8v af[4], bf[4];
#pragma unroll
        for (int rf = 0; rf < 4; ++rf) af[rf] = *(const s8v*)&SA[cur][(lq * 64 + rf * 16 + lr) * 8];
#pragma unroll
        for (int cf = 0; cf < 4; ++cf) bf[cf] = *(const s8v*)&SB[cur][(lq * 256 + w * 64 + cf * 16 + lr) * 8];
#pragma unroll
        for (int rf = 0; rf < 4; ++rf)
#pragma unroll
            for (int cf = 0; cf < 4; ++cf)
                acc[rf][cf] = __builtin_amdgcn_mfma_f32_16x16x32_bf16(af[rf], bf[cf], acc[rf][cf], 0, 0, 0);
        if (ks < 3) {
            *(s8v*)&SA[cur ^ 1][(sg * 64 + srow) * 8] = pa;
#pragma unroll
            for (int it = 0; it < 4; ++it) {
                int c = t + it * 256;
                int g = c & 3, n = c >> 2;
                *(s8v*)&SB[cur ^ 1][(g * 256 + n) * 8] = pb[it];
            }
        }
        __syncthreads();
    }
#pragma unroll
    for (int cf = 0; cf < 4; ++cf) {
        int c = w * 64 + cf * 16 + lr;
#pragma unroll
        for (int rf = 0; rf < 4; ++rf)
#pragma unroll
            for (int i = 0; i < 4; ++i) {
                int row = rf * 16 + lq * 4 + i;
                Hs[((c >> 3) * 64 + row) * 8 + (c & 7)] = f2b(acc[rf][cf][i]);
            }
    }
    __syncthreads();
    // flush h -> hl/hr (coalesced 16B)
#pragma unroll
    for (int it = 0; it < 8; ++it) {
        int c = t + it * 256;
        int row = c >> 5, g = c & 31;
        int node = r0 + row;
        if (node < NN) {
            s8v v = *(const s8v*)&Hs[(g * 64 + row) * 8];
            int cc = g * 8;
            if (cc < 128) *(s8v*)&hl[(size_t)node * 128 + cc] = v;
            else          *(s8v*)&hr[(size_t)node * 128 + cc - 128] = v;
        }
    }
    // alpha epilogue: alc_s/alc_d[node*8 + gat*4 + head]
#pragma unroll
    for (int it = 0; it < 4; ++it) {
        int row = it * 16 + (t >> 4);
        int node = r0 + row;
        int q = t & 15;
        int gat = q >> 3, sd = (q >> 2) & 1, head = q & 3;
        const float* av = gat ? (sd ? reg_ad : reg_as) : (sd ? loc_ad : loc_as);
        float s = 0.f;
        int cbase = gat * 128 + head * 32;
        for (int d = 0; d < 32; ++d) {
            int c = cbase + d;
            s += b2f(Hs[((c >> 3) * 64 + row) * 8 + (c & 7)]) * av[head * 32 + d];
        }
        if (node < NN) {
            float* outp = sd ? alc_d : alc_s;
            outp[(size_t)node * 8 + gat * 4 + head] = s;
        }
    }
    // fused mean-pool partials
    {
        int colp = t & 127, halfp = t >> 7;
        int rbase = r0 + halfp * 32;
        int lastrow = r0 + 63; if (lastrow >= NN) lastrow = NN - 1;
        int blo = batch[r0 < NN ? r0 : NN - 1];
        int bhi = batch[lastrow];
        float acc0 = 0.f, acc1 = 0.f;
        for (int r = 0; r < 32; ++r) {
            int row = rbase + r;
            if (row < NN) {
                float v = x[(size_t)row * 128 + colp];
                int b = batch[row];
                if (b == blo) acc0 += v; else acc1 += v;
            }
        }
        atomicAdd(&pooled[blo * 128 + colp], acc0);
        if (bhi != blo) atomicAdd(&pooled[bhi * 128 + colp], acc1);
    }
}

// ---------------- gfeat: one block per graph ----------------
__global__ __launch_bounds__(256) void k_gfeat8(
    const float* __restrict__ pooled, const int* __restrict__ batch,
    const float* __restrict__ W1, const float* __restrict__ b1,
    const float* __restrict__ W2, const float* __restrict__ b2,
    unsigned short* __restrict__ g8b) {
    __shared__ float mean_s[128];
    __shared__ float hid_s[128];
    __shared__ float part[256];
    __shared__ int bnd[2];
    int b = blockIdx.x, t = threadIdx.x;
    if (t < 2) {
        int target = b + t;
        int lo = 0, hi = NN;
        while (lo < hi) { int mid = (lo + hi) >> 1; if (batch[mid] < target) lo = mid + 1; else hi = mid; }
        bnd[t] = lo;
    }
    __syncthreads();
    int cnt = bnd[1] - bnd[0];
    float inv = cnt ? 1.f / (float)cnt : 0.f;
    if (t < 128) mean_s[t] = pooled[b * 128 + t] * inv;
    __syncthreads();
    int c = t & 127, kh = t >> 7;
    float a = 0.f;
    for (int k = kh * 64; k < kh * 64 + 64; k++) a += mean_s[k] * W1[k * 128 + c];
    part[t] = a;
    __syncthreads();
    if (t < 128) hid_s[t] = fmaxf(part[t] + part[t + 128] + b1[t], 0.f);
    __syncthreads();
    float a2 = 0.f;
    for (int k = kh * 64; k < kh * 64 + 64; k++) a2 += hid_s[k] * W2[k * 128 + c];
    part[t] = a2;
    __syncthreads();
    if (t < 128) g8b[b * 128 + t] = f2b(part[t] + part[t + 128] + b2[t]);
}

// ---------------- GAT aggregate (R5 structure, interleaved alc) ----------------
__global__ __launch_bounds__(256) void k_gat(
    const int* __restrict__ row_ptr, const int* __restrict__ col,
    const unsigned short* __restrict__ hl, const unsigned short* __restrict__ hr,
    const float* __restrict__ alc_s, const float* __restrict__ alc_d,
    const float* __restrict__ x,
    const float* __restrict__ loc_bias, const float* __restrict__ loc_g, const float* __restrict__ loc_b,
    const float* __restrict__ reg_bias, const float* __restrict__ reg_g, const float* __restrict__ reg_b,
    unsigned short* __restrict__ out_local, unsigned short* __restrict__ out_reg) {
    __shared__ float exA[4][64][4];
    __shared__ float exB[4][64][4];
    __shared__ int   colb[4][64];
    __shared__ int   degs[4];
    int w = threadIdx.x >> 6, lane = threadIdx.x & 63;
    int hA = lane >> 4;
    int node = blockIdx.x * 4 + w;
    int rp0 = row_ptr[node];
    int deg = row_ptr[node + 1] - rp0;
    if (lane == 0) degs[w] = deg;
    float4 adL = *(const float4*)&alc_d[(size_t)node * 8];
    float4 adR = *(const float4*)&alc_d[(size_t)node * 8 + 4];
    __syncthreads();
    int maxdeg = max(max(degs[0], degs[1]), max(degs[2], degs[3]));
    int chunks = (maxdeg + 63) >> 6;

    float sL0 = 0.f, sL1 = 0.f, sL2 = 0.f, sL3 = 0.f;
    float sR0 = 0.f, sR1 = 0.f, sR2 = 0.f, sR3 = 0.f;
    for (int base = 0; base < deg; base += 64) {
        int i = base + lane;
        bool v = i < deg;
        int s = col[rp0 + (v ? i : deg - 1)];
        float4 aL = *(const float4*)&alc_s[(size_t)s * 8];
        float4 aR = *(const float4*)&alc_s[(size_t)s * 8 + 4];
        float e0 = __expf(lrelu(aL.x + adL.x));
        float e1 = __expf(lrelu(aL.y + adL.y));
        float e2 = __expf(lrelu(aL.z + adL.z));
        float e3 = __expf(lrelu(aL.w + adL.w));
        float f0 = __expf(lrelu(aR.x + adR.x));
        float f1 = __expf(lrelu(aR.y + adR.y));
        float f2 = __expf(lrelu(aR.z + adR.z));
        float f3 = __expf(lrelu(aR.w + adR.w));
        if (!v) { e0 = e1 = e2 = e3 = f0 = f1 = f2 = f3 = 0.f; }
        *(float4*)&exA[w][lane][0] = make_float4(e0, e1, e2, e3);
        *(float4*)&exB[w][lane][0] = make_float4(f0, f1, f2, f3);
        colb[w][lane] = s;
        sL0 += e0; sL1 += e1; sL2 += e2; sL3 += e3;
        sR0 += f0; sR1 += f1; sR2 += f2; sR3 += f3;
    }
    __syncthreads();
#pragma unroll
    for (int off = 32; off; off >>= 1) {
        sL0 += __shfl_xor(sL0, off); sL1 += __shfl_xor(sL1, off);
        sL2 += __shfl_xor(sL2, off); sL3 += __shfl_xor(sL3, off);
        sR0 += __shfl_xor(sR0, off); sR1 += __shfl_xor(sR1, off);
        sR2 += __shfl_xor(sR2, off); sR3 += __shfl_xor(sR3, off);
    }
    float iA = (hA & 2) ? ((hA & 1) ? 1.f / sL3 : 1.f / sL2)
                        : ((hA & 1) ? 1.f / sL1 : 1.f / sL0);
    float iB = (hA & 2) ? ((hA & 1) ? 1.f / sR3 : 1.f / sR2)
                        : ((hA & 1) ? 1.f / sR1 : 1.f / sR0);

    float a0 = 0.f, a1 = 0.f, b0 = 0.f, b1 = 0.f;
    const unsigned* hlp = (const unsigned*)hl;
    const unsigned* hrp = (const unsigned*)hr;
    if (chunks == 1) {
#pragma unroll 4
        for (int e = 0; e < deg; ++e) {
            int s = colb[w][e];
            float eAv = exA[w][e][hA];
            float eBv = exB[w][e][hA];
            unsigned ul = hlp[(size_t)s * 64 + lane];
            unsigned ur = hrp[(size_t)s * 64 + lane];
            a0 += eAv * uasf(ul << 16);
            a1 += eAv * uasf(ul & 0xffff0000u);
            b0 += eBv * uasf(ur << 16);
            b1 += eBv * uasf(ur & 0xffff0000u);
        }
    } else {
        for (int c = 0; c < chunks; ++c) {
            int base = c * 64, i = base + lane;
            if (i < deg) {
                int s = col[rp0 + i];
                float4 aL = *(const float4*)&alc_s[(size_t)s * 8];
                float4 aR = *(const float4*)&alc_s[(size_t)s * 8 + 4];
                *(float4*)&exA[w][lane][0] = make_float4(
                    __expf(lrelu(aL.x + adL.x)), __expf(lrelu(aL.y + adL.y)),
                    __expf(lrelu(aL.z + adL.z)), __expf(lrelu(aL.w + adL.w)));
                *(float4*)&exB[w][lane][0] = make_float4(
                    __expf(lrelu(aR.x + adR.x)), __expf(lrelu(aR.y + adR.y)),
                    __expf(lrelu(aR.z + adR.z)), __expf(lrelu(aR.w + adR.w)));
                colb[w][lane] = s;
            }
            __syncthreads();
            int nc = deg - base; nc = nc < 0 ? 0 : (nc > 64 ? 64 : nc);
#pragma unroll 4
            for (int e = 0; e < nc; ++e) {
                int s = colb[w][e];
                float eAv = exA[w][e][hA];
                float eBv = exB[w][e][hA];
                unsigned ul = hlp[(size_t)s * 64 + lane];
                unsigned ur = hrp[(size_t)s * 64 + lane];
                a0 += eAv * uasf(ul << 16);
                a1 += eAv * uasf(ul & 0xffff0000u);
                b0 += eBv * uasf(ur << 16);
                b1 += eBv * uasf(ur & 0xffff0000u);
            }
            __syncthreads();
        }
    }

    int f = 2 * lane;
    float2 xr = *(const float2*)&x[(size_t)node * 128 + f];
    float2 lbi = *(const float2*)&loc_bias[f];
    float2 rbi = *(const float2*)&reg_bias[f];
    float v0 = a0 * iA + lbi.x + xr.x;
    float v1 = a1 * iA + lbi.y + xr.y;
    float u0 = b0 * iB + rbi.x + xr.x;
    float u1 = b1 * iB + rbi.y + xr.y;

    float sv = v0 + v1, su = u0 + u1;
#pragma unroll
    for (int off = 32; off; off >>= 1) { sv += __shfl_xor(sv, off); su += __shfl_xor(su, off); }
    float mv = sv * (1.f / 128.f), mu = su * (1.f / 128.f);
    float dv0 = v0 - mv, dv1 = v1 - mv, du0 = u0 - mu, du1 = u1 - mu;
    float qv = dv0 * dv0 + dv1 * dv1, qu = du0 * du0 + du1 * du1;
#pragma unroll
    for (int off = 32; off; off >>= 1) { qv += __shfl_xor(qv, off); qu += __shfl_xor(qu, off); }
    float rv = rsqrtf(qv * (1.f / 128.f) + 1e-5f), ru = rsqrtf(qu * (1.f / 128.f) + 1e-5f);
    float2 lg = *(const float2*)&loc_g[f], lb2 = *(const float2*)&loc_b[f];
    float2 rg = *(const float2*)&reg_g[f], rb2 = *(const float2*)&reg_b[f];
    unsigned pv = (unsigned)f2b(dv0 * rv * lg.x + lb2.x) | ((unsigned)f2b(dv1 * rv * lg.y + lb2.y) << 16);
    unsigned pu = (unsigned)f2b(du0 * ru * rg.x + rb2.x) | ((unsigned)f2b(du1 * ru * rg.y + rb2.y) << 16);
    *(unsigned*)&out_local[(size_t)node * 128 + f] = pv;
    *(unsigned*)&out_reg[(size_t)node * 128 + f]   = pu;
}

// ---------------- fused MLP (MFMA, dbuf LDS) ----------------
__global__ __launch_bounds__(256) void k_fusedm(
    const unsigned short* __restrict__ localb, const unsigned short* __restrict__ regionalb,
    const unsigned short* __restrict__ g8b, const int* __restrict__ batch,
    const unsigned short* __restrict__ W1t, const float* __restrict__ b1,
    const unsigned short* __restrict__ W2t, const float* __restrict__ b2,
    const float* __restrict__ lng, const float* __restrict__ lnb,
    float* __restrict__ out) {
    __shared__ __align__(16) unsigned short stg[20480];  // 40KB staging (layer1 A/B dbuf; layer2 W2 dbuf)
    __shared__ __align__(16) unsigned short Hs[16384];   // 32KB hidden
    unsigned short* SAb[2] = { stg, stg + 2048 };                 // 2x 4KB
    unsigned short* SBb[2] = { stg + 4096, stg + 12288 };         // 2x 16KB
    unsigned short* W2Sb[2] = { stg, stg + 4096 };                // 2x 8KB (overlaid, layer2)
    int t = threadIdx.x;
    int w = t >> 6, l = t & 63;
    int lq = l >> 4, lr = l & 15;
    int r0 = blockIdx.x * 64;

    int srow = t >> 2, sg = t & 3;
    int snode = r0 + srow; if (snode >= NN) snode = NN - 1;
    int sbatch = batch[snode];

    auto asrc = [&](int ks) -> const unsigned short* {
        int seg = ks >> 2;
        int ko = (ks & 3) * 32 + sg * 8;
        return seg == 0 ? localb + (size_t)snode * 128 + ko :
               seg == 1 ? regionalb + (size_t)snode * 128 + ko :
                          g8b + (size_t)sbatch * 128 + ko;
    };

    f4v acc[4][4];
#pragma unroll
    for (int a0 = 0; a0 < 4; a0++)
#pragma unroll
        for (int b0 = 0; b0 < 4; b0++) acc[a0][b0] = (f4v){0.f, 0.f, 0.f, 0.f};

    // prologue: stage ks=0
    *(s8v*)&SAb[0][(sg * 64 + srow) * 8] = *(const s8v*)asrc(0);
#pragma unroll
    for (int it = 0; it < 4; ++it) {
        int c = t + it * 256;
        int g = c & 3, n = c >> 2;
        *(s8v*)&SBb[0][(g * 256 + n) * 8] = *(const s8v*)&W1t[(size_t)n * 384 + g * 8];
    }
    __syncthreads();
#pragma unroll
    for (int ks = 0; ks < 12; ++ks) {
        int cur = ks & 1;
        s8v pa; s8v pb[4];
        if (ks < 11) {
            pa = *(const s8v*)asrc(ks + 1);
#pragma unroll
            for (int it = 0; it < 4; ++it) {
                int c = t + it * 256;
                int g = c & 3, n = c >> 2;
                pb[it] = *(const s8v*)&W1t[(size_t)n * 384 + (ks + 1) * 32 + g * 8];
            }
        }
        s8v af[4], bf[4];
#pragma unroll
        for (int rf = 0; rf < 4; ++rf) af[rf] = *(const s8v*)&SAb[cur][(lq * 64 + rf * 16 + lr) * 8];
#pragma unroll
        for (int cf = 0; cf < 4; ++cf) bf[cf] = *(const s8v*)&SBb[cur][(lq * 256 + w * 64 + cf * 16 + lr) * 8];
#pragma unroll
        for (int rf = 0; rf < 4; ++rf)
#pragma unroll
            for (int cf = 0; cf < 4; ++cf)
                acc[rf][cf] = __builtin_amdgcn_mfma_f32_16x16x32_bf16(af[rf], bf[cf], acc[rf][cf], 0, 0, 0);
        if (ks < 11) {
            *(s8v*)&SAb[cur ^ 1][(sg * 64 + srow) * 8] = pa;
#pragma unroll
            for (int it = 0; it < 4; ++it) {
                int c = t + it * 256;
                int g = c & 3, n = c >> 2;
                *(s8v*)&SBb[cur ^ 1][(g * 256 + n) * 8] = pb[it];
            }
        }
        __syncthreads();
    }
    // epilogue 1: bias + relu -> Hs (bf16)
#pragma unroll
    for (int cf = 0; cf < 4; ++cf) {
        int c = w * 64 + cf * 16 + lr;
        float bc = b1[c];
#pragma unroll
        for (int rf = 0; rf < 4; ++rf)
#pragma unroll
            for (int i = 0; i < 4; ++i) {
                int row = rf * 16 + lq * 4 + i;
                float v0 = acc[rf][cf][i] + bc;
                Hs[((c >> 3) * 64 + row) * 8 + (c & 7)] = f2b(v0 > 0.f ? v0 : 0.f);
            }
    }
    // stage W2 ks=0 into overlay (layer1 staging is dead; guard with barrier)
    __syncthreads();
#pragma unroll
    for (int it = 0; it < 2; ++it) {
        int c = t + it * 256;
        int g = c & 3, n = c >> 2;
        *(s8v*)&W2Sb[0][(g * 128 + n) * 8] = *(const s8v*)&W2t[(size_t)n * 256 + g * 8];
    }
    __syncthreads();
    f4v a2[8];
#pragma unroll
    for (int cf = 0; cf < 8; ++cf) a2[cf] = (f4v){0.f, 0.f, 0.f, 0.f};
#pragma unroll
    for (int ks = 0; ks < 8; ++ks) {
        int cur = ks & 1;
        s8v pw[2];
        if (ks < 7) {
#pragma unroll
            for (int it = 0; it < 2; ++it) {
                int c = t + it * 256;
                int g = c & 3, n = c >> 2;
                pw[it] = *(const s8v*)&W2t[(size_t)n * 256 + (ks + 1) * 32 + g * 8];
            }
        }
        s8v af = *(const s8v*)&Hs[((ks * 4 + lq) * 64 + w * 16 + lr) * 8];
#pragma unroll
        for (int cf = 0; cf < 8; ++cf) {
            s8v bfv = *(const s8v*)&W2Sb[cur][(lq * 128 + cf * 16 + lr) * 8];
            a2[cf] = __builtin_amdgcn_mfma_f32_16x16x32_bf16(af, bfv, a2[cf], 0, 0, 0);
        }
        if (ks < 7) {
#pragma unroll
            for (int it = 0; it < 2; ++it) {
                int c = t + it * 256;
                int g = c & 3, n = c >> 2;
                *(s8v*)&W2Sb[cur ^ 1][(g * 128 + n) * 8] = pw[it];
            }
        }
        __syncthreads();
    }
    float b2c[8], gc[8], bc2[8];
#pragma unroll
    for (int cf = 0; cf < 8; ++cf) {
        int c = cf * 16 + lr;
        b2c[cf] = b2[c]; gc[cf] = lng[c]; bc2[cf] = lnb[c];
    }
#pragma unroll
    for (int i = 0; i < 4; ++i) {
        int row = w * 16 + lq * 4 + i;
        int node = r0 + row;
        float vals[8]; float s = 0.f;
#pragma unroll
        for (int cf = 0; cf < 8; ++cf) { vals[cf] = a2[cf][i] + b2c[cf]; s += vals[cf]; }
        s += __shfl_xor(s, 1); s += __shfl_xor(s, 2); s += __shfl_xor(s, 4); s += __shfl_xor(s, 8);
        float mean = s * (1.f / 128.f);
        float vs = 0.f;
#pragma unroll
        for (int cf = 0; cf < 8; ++cf) { float d = vals[cf] - mean; vs += d * d; }
        vs += __shfl_xor(vs, 1); vs += __shfl_xor(vs, 2); vs += __shfl_xor(vs, 4); vs += __shfl_xor(vs, 8);
        float rstd = rsqrtf(vs * (1.f / 128.f) + 1e-5f);
        if (node < NN) {
#pragma unroll
            for (int cf = 0; cf < 8; ++cf)
                out[(size_t)node * 128 + cf * 16 + lr] = (vals[cf] - mean) * rstd * gc[cf] + bc2[cf];
        }
    }
}

extern "C" void kernel_launch(void* const* d_in, const int* in_sizes, int n_in,
                              void* d_out, int out_size, void* d_ws, size_t ws_size,
                              hipStream_t stream) {
    const float* x      = (const float*)d_in[0];
    const int*   ei     = (const int*)d_in[1];
    const int*   batch  = (const int*)d_in[2];
    const float* locW   = (const float*)d_in[3];
    const float* loc_as = (const float*)d_in[4];
    const float* loc_ad = (const float*)d_in[5];
    const float* loc_bi = (const float*)d_in[6];
    const float* loc_g  = (const float*)d_in[7];
    const float* loc_b  = (const float*)d_in[8];
    const float* regW   = (const float*)d_in[9];
    const float* reg_as = (const float*)d_in[10];
    const float* reg_ad = (const float*)d_in[11];
    const float* reg_bi = (const float*)d_in[12];
    const float* reg_g  = (const float*)d_in[13];
    const float* reg_b  = (const float*)d_in[14];
    const float* gp_W1  = (const float*)d_in[15];
    const float* gp_b1  = (const float*)d_in[16];
    const float* gp_W2  = (const float*)d_in[17];
    const float* gp_b2  = (const float*)d_in[18];
    const float* fu_W1  = (const float*)d_in[19];
    const float* fu_b1  = (const float*)d_in[20];
    const float* fu_W2  = (const float*)d_in[21];
    const float* fu_b2  = (const float*)d_in[22];
    const float* fu_lg  = (const float*)d_in[23];
    const float* fu_lb  = (const float*)d_in[24];
    float* out = (float*)d_out;

    char* ws = (char*)d_ws;
    size_t off = 0;
    auto alloc = [&](size_t bytes) { void* p = ws + off; off += (bytes + 255) & ~(size_t)255; return p; };
    unsigned short* hl        = (unsigned short*)alloc((size_t)NN * 128 * 2);
    unsigned short* hr        = (unsigned short*)alloc((size_t)NN * 128 * 2);
    unsigned short* localb    = (unsigned short*)alloc((size_t)NN * 128 * 2);
    unsigned short* regionalb = (unsigned short*)alloc((size_t)NN * 128 * 2);
    float* alc_s  = (float*)alloc((size_t)NN * 8 * 4);
    float* alc_d  = (float*)alloc((size_t)NN * 8 * 4);
    int* row_ptr  = (int*)alloc((size_t)(NN + 1) * 4);
    int* cur      = (int*)alloc((size_t)NN * 4);
    int* col      = (int*)alloc((size_t)(EE + NN) * 4);
    float* pooled = (float*)alloc((size_t)BB * 128 * 4);
    unsigned short* g8b = (unsigned short*)alloc((size_t)BB * 128 * 2);
    unsigned short* Wt  = (unsigned short*)alloc((size_t)32768 * 2);
    unsigned short* W1t = (unsigned short*)alloc((size_t)98304 * 2);
    unsigned short* W2t = (unsigned short*)alloc((size_t)32768 * 2);
    int* bsum = (int*)alloc((size_t)NBLK * 4);

    hipLaunchKernelGGL(k_prep, dim3(640 + NBLK), dim3(256), 0, stream,
                       locW, regW, fu_W1, fu_W2, Wt, W1t, W2t, cur, pooled);
    hipLaunchKernelGGL(k_count, dim3((EE + 255) / 256), dim3(256), 0, stream, ei, cur);
    hipLaunchKernelGGL(k_scanA, dim3(NBLK), dim3(256), 0, stream, cur, row_ptr, bsum);
    hipLaunchKernelGGL(k_scanC, dim3(NBLK), dim3(256), 0, stream, row_ptr, bsum);
    hipLaunchKernelGGL(k_scatter, dim3((EE + NN + 255) / 256), dim3(256), 0, stream, ei, row_ptr, cur, col);
    hipLaunchKernelGGL(k_gemm1, dim3((NN + 63) / 64), dim3(256), 0, stream,
                       x, batch, Wt, loc_as, loc_ad, reg_as, reg_ad,
                       hl, hr, alc_s, alc_d, pooled);
    hipLaunchKernelGGL(k_gfeat8, dim3(BB), dim3(256), 0, stream,
                       pooled, batch, gp_W1, gp_b1, gp_W2, gp_b2, g8b);
    hipLaunchKernelGGL(k_gat, dim3(NN / 4), dim3(256), 0, stream,
                       row_ptr, col, hl, hr, alc_s, alc_d, x,
                       loc_bi, loc_g, loc_b, reg_bi, reg_g, reg_b,
                       localb, regionalb);
    hipLaunchKernelGGL(k_fusedm, dim3((NN + 63) / 64), dim3(256), 0, stream,
                       localb, regionalb, g8b, batch,
                       W1t, fu_b1, W2t, fu_b2, fu_lg, fu_lb, out);
}